// Round 8
// baseline (505.079 us; speedup 1.0000x reference)
//
#include <hip/hip_runtime.h>
#include <hip/hip_bf16.h>

// Problem constants (static per reference)
#define NN   512    // nodes
#define EE   512    // edges == nb-graph nodes (En)
#define MM   16384  // nb-graph edges
#define PCAP2 6291456  // pair-buffer capacity (actual ~524K)

typedef float v4f __attribute__((ext_vector_type(4)));
typedef short short8v __attribute__((ext_vector_type(8)));

__device__ __forceinline__ float silu_f(float v) { return v / (1.0f + __expf(-v)); }

// ---------------- K1: per original edge: coord_diff + efn = MLP([h_r|h_c]) ----
__global__ __launch_bounds__(128) void k_edge(
    const float* __restrict__ h, const float* __restrict__ x,
    const int* __restrict__ edges,
    const float* __restrict__ ew1, const float* __restrict__ eb1,
    const float* __restrict__ ew2, const float* __restrict__ eb2,
    float* __restrict__ coord_diff, float* __restrict__ efn) {
  __shared__ float hin[128];
  __shared__ float hs[128];
  int e = blockIdx.x;
  int t = threadIdx.x;
  int r = edges[e], c = edges[EE + e];
  if (t < 3) coord_diff[e * 3 + t] = x[r * 3 + t] - x[c * 3 + t];
  if (t < 64) { hin[t] = h[r * 64 + t]; hin[64 + t] = h[c * 64 + t]; }
  __syncthreads();
  float acc = eb1[t];
  for (int k = 0; k < 128; ++k) acc += hin[k] * ew1[k * 128 + t];
  hs[t] = silu_f(acc);
  __syncthreads();
  if (t < 64) {
    float o = eb2[t];
    for (int k = 0; k < 128; ++k) o += hs[k] * ew2[k * 64 + t];
    efn[e * 64 + t] = o;
  }
}

// ---------------- K2: constants c1 = MLP1(0), c2 = MLP2(0) -------------------
__global__ __launch_bounds__(128) void k_consts(
    const float* __restrict__ p1b1, const float* __restrict__ p1w2, const float* __restrict__ p1b2,
    const float* __restrict__ p2b1, const float* __restrict__ p2w2, const float* __restrict__ p2b2,
    float* __restrict__ c1, float* __restrict__ c2) {
  __shared__ float h1[128], h2[128];
  int t = threadIdx.x;
  h1[t] = silu_f(p1b1[t]); h2[t] = silu_f(p2b1[t]);
  __syncthreads();
  if (t < 64) {
    float a1 = p1b2[t], a2 = p2b2[t];
    for (int k = 0; k < 128; ++k) { a1 += h1[k] * p1w2[k * 64 + t]; a2 += h2[k] * p2w2[k * 64 + t]; }
    c1[t] = a1; c2[t] = a2;
  }
}

// ---------------- K2b: Wt[h][f] = bf16(p3w1[96+f][h]) (B-operand for MFMA) ---
__global__ __launch_bounds__(256) void k_prep(const float* __restrict__ p3w1,
                                              __hip_bfloat16* __restrict__ Wt) {
  int e = blockIdx.x * 256 + threadIdx.x;   // 8192 = 128 h x 64 f
  int hh = e >> 6, f = e & 63;
  Wt[hh * 64 + f] = __float2bfloat16(p3w1[(96 + f) * 128 + hh]);
}

// ---------------- K3: mark touched cells -------------------------------------
__global__ __launch_bounds__(256) void k_mark(const int* __restrict__ nb_edge,
                                              int* __restrict__ slotmap) {
  int m = blockIdx.x * 256 + threadIdx.x;
  if (m >= MM) return;
  int cell = nb_edge[m] * 512 + nb_edge[MM + m];
  atomicCAS(&slotmap[cell], -1, -2);
}

// ------ K4: compact marked cells -> slots, row histogram + bucket histogram --
__global__ __launch_bounds__(256) void k_compact(int* __restrict__ slotmap,
                                                 int* __restrict__ cells,
                                                 int* __restrict__ nC,
                                                 int* __restrict__ cntA,
                                                 int* __restrict__ cnt8) {
  int cell = blockIdx.x * 256 + threadIdx.x;
  if (slotmap[cell] != -2) return;
  int s = atomicAdd(nC, 1);
  slotmap[cell] = s;
  cells[s] = cell;
  atomicAdd(&cntA[cell >> 9], 1);                              // by first coord a
  atomicAdd(&cnt8[(cell >> 9) * 8 + ((cell & 511) >> 6)], 1);  // by (a, j>>6)
}

// ---------------- K5: prefix sum for the row CSR -----------------------------
__global__ __launch_bounds__(512) void k_scan(const int* __restrict__ cntA,
                                              int* __restrict__ offA,
                                              int* __restrict__ curA) {
  __shared__ int sA[512];
  int t = threadIdx.x;
  int a0 = cntA[t];
  sA[t] = a0;
  for (int off = 1; off < 512; off <<= 1) {
    __syncthreads();
    int a = (t >= off) ? sA[t - off] : 0;
    __syncthreads();
    sA[t] += a;
  }
  __syncthreads();
  offA[t] = sA[t] - a0;
  curA[t] = sA[t] - a0;
}

// ---------------- K5b: generic 4096-element exclusive scan -------------------
__global__ __launch_bounds__(1024) void k_scan4096(
    const int* __restrict__ cntIn, int* __restrict__ offOut, int* __restrict__ curOut) {
  __shared__ int part[1024];
  int t = threadIdx.x;
  int v[4]; int sum = 0;
#pragma unroll
  for (int ii = 0; ii < 4; ++ii) { v[ii] = cntIn[t * 4 + ii]; sum += v[ii]; }
  part[t] = sum;
  for (int off = 1; off < 1024; off <<= 1) {
    __syncthreads();
    int a = (t >= off) ? part[t - off] : 0;
    __syncthreads();
    part[t] += a;
  }
  __syncthreads();
  int r = part[t] - sum;
#pragma unroll
  for (int ii = 0; ii < 4; ++ii) {
    offOut[t * 4 + ii] = r; curOut[t * 4 + ii] = r; r += v[ii];
  }
}

// -------- K6: fill row CSR list, packing slot | (second-coord << 18) ---------
__global__ __launch_bounds__(256) void k_fill(const int* __restrict__ cells, const int* __restrict__ nC,
                                              int* __restrict__ curA,
                                              int* __restrict__ listAJ) {
  int s = blockIdx.x * 256 + threadIdx.x;
  if (s >= *nC) return;
  int cell = cells[s];
  listAJ[atomicAdd(&curA[cell >> 9], 1)] = s | ((cell & 511) << 18);
}

// -------- K6b: fill bucketed cell list, packing slot | (j&63)<<18 ------------
__global__ __launch_bounds__(256) void k_fill8(const int* __restrict__ cells, const int* __restrict__ nC,
                                               int* __restrict__ cur8,
                                               int* __restrict__ listS8) {
  int s = blockIdx.x * 256 + threadIdx.x;
  if (s >= *nC) return;
  int cell = cells[s];
  int a = cell >> 9, b = cell & 511;
  listS8[atomicAdd(&cur8[a * 8 + (b >> 6)], 1)] = s | ((b & 63) << 18);
}

// -------- K6c: pair counts per (row i, jr): pc = sum over row cells of cnt8 --
__global__ __launch_bounds__(64) void k_pcnt(
    const int* __restrict__ cntA, const int* __restrict__ offA,
    const int* __restrict__ listAJ, const int* __restrict__ cnt8,
    int* __restrict__ pc) {
  __shared__ int acc[64];
  int i = blockIdx.x, t = threadIdx.x;
  int jr = t & 7, par = t >> 3;
  int n1 = cntA[i], o1 = offA[i];
  int s = 0;
  for (int q = par; q < n1; q += 8) {
    int k = listAJ[o1 + q] >> 18;
    s += cnt8[k * 8 + jr];
  }
  acc[t] = s;
  __syncthreads();
  if (t < 8) {
    int tot = 0;
    for (int pp = 0; pp < 8; ++pp) tot += acc[pp * 8 + t];
    pc[i * 8 + t] = tot;
  }
}

// -------- K6d: fill flat pair buffer, bucketed by (row i, jr) ----------------
__global__ __launch_bounds__(64) void k_pfill2(
    const int* __restrict__ nC, const int* __restrict__ cells,
    const int* __restrict__ listAJ,
    const int* __restrict__ cnt8, const int* __restrict__ off8,
    const int* __restrict__ listS8,
    int* __restrict__ cur2, uint2* __restrict__ pairBuf) {
  __shared__ int baseS[8];
  int q = blockIdx.x;
  if (q >= *nC) return;
  int e1 = listAJ[q];
  int s1 = e1 & 0x3FFFF;
  int k = e1 >> 18;
  int i = cells[s1] >> 9;
  int t = threadIdx.x;
  if (t < 8) {
    int nn = cnt8[k * 8 + t];
    baseS[t] = nn ? atomicAdd(&cur2[i * 8 + t], nn) : 0;
  }
  __syncthreads();
  for (int jr = 0; jr < 8; ++jr) {
    int nn = cnt8[k * 8 + jr], oo = off8[k * 8 + jr], bb = baseS[jr];
    for (int e = t; e < nn; e += 64)
      if (bb + e < PCAP2)
        pairBuf[bb + e] = make_uint2((unsigned)s1, (unsigned)listS8[oo + e]);
  }
}

// ---------------- K7: nb_feat scatter-add into COMPACT Tc (2 edges/block) ----
__global__ __launch_bounds__(192) void k_scatterT(
    const int* __restrict__ nb_edge, const int* __restrict__ slotmap,
    const float* __restrict__ coord_diff, const float* __restrict__ efn,
    float* __restrict__ Tc) {
  int t = threadIdx.x;
  int sub = (t >= 96) ? 1 : 0;
  int c = t - sub * 96;
  int m = blockIdx.x * 2 + sub;
  int a = nb_edge[m], b = nb_edge[MM + m];
  int s = slotmap[a * 512 + b];
  float val;
  if (c < 32) {
    float vtv = coord_diff[a * 3 + 0] * coord_diff[b * 3 + 0]
              + coord_diff[a * 3 + 1] * coord_diff[b * 3 + 1]
              + coord_diff[a * 3 + 2] * coord_diff[b * 3 + 2];
    int i = c >> 1;
    float ang = vtv * 16.0f * __expf(-0.57564627324851143f * (float)i);
    val = (c & 1) ? cosf(ang) : sinf(ang);
  } else {
    int f = c - 32;
    val = efn[a * 64 + f] * efn[b * 64 + f];
  }
  atomicAdd(&Tc[s * 96 + c], val);
}

// ------- K8: batched (8 cells/block) MLPs -> D1/D2, sums A,B; TWc = Tc@w1T ---
__global__ __launch_bounds__(128) void k_mlp96b(
    const int* __restrict__ cells, const int* __restrict__ nC, const float* __restrict__ Tc,
    const float* __restrict__ w11, const float* __restrict__ b11,
    const float* __restrict__ w12, const float* __restrict__ b12,
    const float* __restrict__ w21, const float* __restrict__ b21,
    const float* __restrict__ w22, const float* __restrict__ b22,
    const float* __restrict__ c1, const float* __restrict__ c2,
    const float* __restrict__ p3w1,
    float* __restrict__ D1, float* __restrict__ D2,
    float* __restrict__ A, float* __restrict__ B,
    float* __restrict__ TWc) {
  __shared__ float xsT[96 * 8];    // [k][cell] transposed for b128 reads
  __shared__ float hid[8][128];
  __shared__ int cl[8];
  int t = threadIdx.x;
  int nc = *nC;
  int s0 = blockIdx.x * 8;
  if (s0 >= nc) return;
  for (int e = t; e < 768; e += 128) xsT[(e % 96) * 8 + e / 96] = Tc[s0 * 96 + e];
  if (t < 8) cl[t] = (s0 + t < nc) ? cells[s0 + t] : 0;
  __syncthreads();
  float tw[8], a1[8], a2[8];
#pragma unroll
  for (int c = 0; c < 8; ++c) { tw[c] = 0.f; a1[c] = b11[t]; a2[c] = b21[t]; }
  for (int k = 0; k < 96; ++k) {
    float wt = p3w1[k * 128 + t];
    float w1v = w11[k * 128 + t];
    float w2v = w21[k * 128 + t];
    float4 xlo = *(const float4*)&xsT[k * 8];
    float4 xhi = *(const float4*)&xsT[k * 8 + 4];
    float xv[8] = {xlo.x, xlo.y, xlo.z, xlo.w, xhi.x, xhi.y, xhi.z, xhi.w};
#pragma unroll
    for (int c = 0; c < 8; ++c) {
      tw[c] += xv[c] * wt; a1[c] += xv[c] * w1v; a2[c] += xv[c] * w2v;
    }
  }
#pragma unroll
  for (int c = 0; c < 8; ++c) {
    if (s0 + c < nc) TWc[(s0 + c) * 128 + t] = tw[c];
    hid[c][t] = silu_f(a1[c]);
  }
  __syncthreads();
  {
    int hh = t & 63, cq = t >> 6;
    float o[4];
#pragma unroll
    for (int cc = 0; cc < 4; ++cc) o[cc] = b12[hh];
    for (int k = 0; k < 128; ++k) {
      float w = w12[k * 64 + hh];
#pragma unroll
      for (int cc = 0; cc < 4; ++cc) o[cc] += hid[cq * 4 + cc][k] * w;
    }
#pragma unroll
    for (int cc = 0; cc < 4; ++cc) {
      int c = cq * 4 + cc;
      if (s0 + c < nc) {
        float d = o[cc] - c1[hh];
        D1[(s0 + c) * 64 + hh] = d;
        atomicAdd(&A[(cl[c] >> 9) * 64 + hh], d);
      }
    }
  }
  __syncthreads();
#pragma unroll
  for (int c = 0; c < 8; ++c) hid[c][t] = silu_f(a2[c]);
  __syncthreads();
  {
    int hh = t & 63, cq = t >> 6;
    float o[4];
#pragma unroll
    for (int cc = 0; cc < 4; ++cc) o[cc] = b22[hh];
    for (int k = 0; k < 128; ++k) {
      float w = w22[k * 64 + hh];
#pragma unroll
      for (int cc = 0; cc < 4; ++cc) o[cc] += hid[cq * 4 + cc][k] * w;
    }
#pragma unroll
    for (int cc = 0; cc < 4; ++cc) {
      int c = cq * 4 + cc;
      if (s0 + c < nc) {
        float d = o[cc] - c2[hh];
        D2[(s0 + c) * 64 + hh] = d;
        atomicAdd(&B[(cl[c] & 511) * 64 + hh], d);
      }
    }
  }
}

// ---------------- K10: u[i] = b1 + (512 c1c2 + c2*A[i])@w1m ; v[j] = (c1*B[j])@w1m
__global__ __launch_bounds__(128) void k_uv(
    const float* __restrict__ A, const float* __restrict__ B,
    const float* __restrict__ c1, const float* __restrict__ c2,
    const float* __restrict__ p3w1, const float* __restrict__ p3b1,
    float* __restrict__ u, float* __restrict__ v) {
  __shared__ float vec[64];
  int i = blockIdx.x, y = blockIdx.y, t = threadIdx.x;
  if (t < 64)
    vec[t] = (y == 0) ? (512.0f * c1[t] * c2[t] + c2[t] * A[i * 64 + t])
                      : (c1[t] * B[i * 64 + t]);
  __syncthreads();
  float a = (y == 0) ? p3b1[t] : 0.f;
  for (int f = 0; f < 64; ++f) a += vec[f] * p3w1[(96 + f) * 128 + t];
  (y == 0 ? u : v)[i * 128 + t] = a;
}

// ---------------- K11: S accumulation, wave-private j-slabs, NO BARRIERS -----
// Grid (512 rows, 2); block 256 = 4 waves. Wave w owns jr = grp*4+w, i.e. a
// fixed 64-j slab [64j][64f] fp32 in LDS (f = lane). Flat bucketed pair list:
// per pair, lanes touch distinct f of one j -> no atomics, no syncthreads;
// same-j RAW across iterations ordered by the in-order LDS pipe. 2-deep
// prefetch keeps pair entries + D-rows in flight. Dense bf16 writeback.
__global__ __launch_bounds__(256) void k_spmm(
    const int* __restrict__ pOff2, const int* __restrict__ pc,
    const uint2* __restrict__ pairBuf,
    const float* __restrict__ D1, const float* __restrict__ D2,
    __hip_bfloat16* __restrict__ S) {
  __shared__ float slabs[4][4096];   // 64 KB
  int i = blockIdx.x;
  int w = threadIdx.x >> 6, lane = threadIdx.x & 63;
  int jr = blockIdx.y * 4 + w;
  float* slab = slabs[w];
  for (int e = lane; e < 4096; e += 64) slab[e] = 0.f;
  int n = pc[i * 8 + jr], base = pOff2[i * 8 + jr];
  uint2 e_c = make_uint2(0u, 0u), e_n = make_uint2(0u, 0u);
  float d1c = 0.f, d2c = 0.f;
  if (n > 0) {
    e_c = pairBuf[base];
    d1c = D1[e_c.x * 64 + lane];
    d2c = D2[(e_c.y & 0x3FFFF) * 64 + lane];
  }
  if (n > 1) e_n = pairBuf[base + 1];
  for (int p = 0; p < n; ++p) {
    uint2 e_nn = make_uint2(0u, 0u);
    if (p + 2 < n) e_nn = pairBuf[base + p + 2];
    float d1n = 0.f, d2n = 0.f;
    if (p + 1 < n) {
      d1n = D1[e_n.x * 64 + lane];
      d2n = D2[(e_n.y & 0x3FFFF) * 64 + lane];
    }
    int jloc = e_c.y >> 18;
    slab[jloc * 64 + lane] += d1c * d2c;   // distinct f per lane; FIFO-ordered
    e_c = e_n; e_n = e_nn; d1c = d1n; d2c = d2n;
  }
  int j0 = jr * 64;
  for (int jl = 0; jl < 64; ++jl)
    S[(i * 512 + j0 + jl) * 64 + lane] = __float2bfloat16(slab[jl * 64 + lane]);
}

// ------- K12: MFMA z = S@Wt + u[i]+v[j]+TW, silu, row/col/diag reduce --------
// Block = 8x8 cells (bi,bj); 4 waves; wave w owns cells w*16..w*16+15.
// C layout: h = n0+(lane&15), cell = w*16 + quad*4 + reg  [m89-verified].
__global__ __launch_bounds__(256) void k_tout_mfma(
    const __hip_bfloat16* __restrict__ S, const float* __restrict__ u,
    const float* __restrict__ v, const float* __restrict__ TWc,
    const int* __restrict__ slotmap, const __hip_bfloat16* __restrict__ Wt,
    float* __restrict__ row_part, float* __restrict__ col_part,
    float* __restrict__ diag_silu) {
  __shared__ __hip_bfloat16 WtL[128 * 72];   // 18,432 B (pad 72 -> 2-way banks)
  __shared__ float uvL[2048];                // u rows | v rows, 8 KB
  __shared__ float colbuf[4][8][128];        // 16 KB
  __shared__ int slotL[64];
  int t = threadIdx.x;
  int w = t >> 6, lane = t & 63;
  int q = lane >> 4, l15 = lane & 15;
  int bi = blockIdx.x >> 6, bj = blockIdx.x & 63;
  int i0 = bi * 8, j0 = bj * 8;
  for (int e = t; e < 4096; e += 256) {
    int row = e >> 5, c2 = e & 31;
    ((unsigned*)WtL)[row * 36 + c2] = ((const unsigned*)Wt)[row * 32 + c2];
  }
  for (int e = t; e < 1024; e += 256) uvL[e] = u[(i0 + (e >> 7)) * 128 + (e & 127)];
  for (int e = t; e < 1024; e += 256) uvL[1024 + e] = v[(j0 + (e >> 7)) * 128 + (e & 127)];
  if (t < 64) slotL[t] = slotmap[(i0 + (t >> 3)) * 512 + j0 + (t & 7)];
  int cellA = w * 16 + l15;
  const short8v* sp = (const short8v*)&S[((i0 + (cellA >> 3)) * 512 + j0 + (cellA & 7)) * 64];
  short8v a0 = sp[q];
  short8v a1 = sp[4 + q];
  __syncthreads();
  v4f acc[8];
#pragma unroll
  for (int nt = 0; nt < 8; ++nt) {
    const short8v* b0 = (const short8v*)&WtL[(nt * 16 + l15) * 72 + q * 8];
    const short8v* b1 = (const short8v*)&WtL[(nt * 16 + l15) * 72 + 32 + q * 8];
    v4f c = {0.f, 0.f, 0.f, 0.f};
    c = __builtin_amdgcn_mfma_f32_16x16x32_bf16(a0, *b0, c, 0, 0, 0);
    c = __builtin_amdgcn_mfma_f32_16x16x32_bf16(a1, *b1, c, 0, 0, 0);
    acc[nt] = c;
  }
  float colp[8][4];
#pragma unroll
  for (int nt = 0; nt < 8; ++nt) {
    int hh = nt * 16 + l15;
    float rsum = 0.f;
#pragma unroll
    for (int r = 0; r < 4; ++r) {
      int c = w * 16 + q * 4 + r;
      int iL = c >> 3, jL = c & 7;
      float z = acc[nt][r] + uvL[iL * 128 + hh] + uvL[1024 + jL * 128 + hh];
      int s = slotL[c];
      if (s >= 0) z += TWc[s * 128 + hh];
      float sv = silu_f(z);
      rsum += sv;
      colp[nt][r] = sv + __shfl_xor(sv, 32);
      if (bi == bj && iL == jL) diag_silu[(i0 + iL) * 128 + hh] = sv;
    }
    rsum += __shfl_xor(rsum, 16);
    if ((q & 1) == 0)
      row_part[(bj * 512 + i0 + 2 * w + (q >> 1)) * 128 + hh] = rsum;
  }
  if (q < 2) {
#pragma unroll
    for (int nt = 0; nt < 8; ++nt)
#pragma unroll
      for (int r = 0; r < 4; ++r)
        colbuf[w][q * 4 + r][nt * 16 + l15] = colp[nt][r];
  }
  __syncthreads();
  for (int e = t; e < 1024; e += 256) {
    int jL = e >> 7, hh = e & 127;
    float a = colbuf[0][jL][hh] + colbuf[1][jL][hh] + colbuf[2][jL][hh] + colbuf[3][jL][hh];
    col_part[(bi * 512 + j0 + jL) * 128 + hh] = a;
  }
}

// ---------------- K13: reduce 64 partial slices ------------------------------
__global__ __launch_bounds__(256) void k_sumparts(
    const float* __restrict__ row_part, const float* __restrict__ col_part,
    float* __restrict__ rowsum, float* __restrict__ colsum) {
  int i = blockIdx.x, t = threadIdx.x;
  const float* src = (t < 128) ? row_part : col_part;
  float* dst = (t < 128) ? rowsum : colsum;
  int hc = t & 127;
  float a = 0.f;
  for (int p = 0; p < 64; ++p) a += src[(p * 512 + i) * 128 + hc];
  dst[i * 128 + hc] = a;
}

// ---------------- K14: second layer of p3 MLP on reduced silu sums -----------
__global__ __launch_bounds__(64) void k_tout2(
    const float* __restrict__ diag_silu, const float* __restrict__ rowsum_silu,
    const float* __restrict__ colsum_silu,
    const float* __restrict__ w2, const float* __restrict__ b2,
    float* __restrict__ diag_T, float* __restrict__ row_T, float* __restrict__ col_T) {
  __shared__ float in[128];
  int e = blockIdx.x, which = blockIdx.y, t = threadIdx.x;
  const float* src = (which == 0) ? diag_silu : (which == 1) ? rowsum_silu : colsum_silu;
  in[t] = src[e * 128 + t]; in[64 + t] = src[e * 128 + 64 + t];
  __syncthreads();
  float a = 0.f;
  for (int k = 0; k < 128; ++k) a += in[k] * w2[k * 64 + t];
  float bias = b2[t] * ((which == 0) ? 1.0f : 512.0f);
  float* dst = (which == 0) ? diag_T : (which == 1) ? row_T : col_T;
  dst[e * 64 + t] = a + bias;
}

// ---------------- K15: tot / tr ----------------------------------------------
__global__ __launch_bounds__(128) void k_totr(
    const float* __restrict__ row_T, const float* __restrict__ diag_T,
    float* __restrict__ tot, float* __restrict__ tr) {
  int t = threadIdx.x;
  const float* src = (t < 64) ? row_T : diag_T;
  int f = t & 63;
  float a = 0.f;
  for (int e = 0; e < 512; ++e) a += src[e * 64 + f];
  if (t < 64) tot[f] = a; else tr[f] = a;
}

// ---------------- K16: nb_t1 = [diag|row|col|tot|tr] @ ign_w + ign_b ---------
__global__ __launch_bounds__(64) void k_nbt1(
    const float* __restrict__ diag_T, const float* __restrict__ row_T,
    const float* __restrict__ col_T, const float* __restrict__ tot,
    const float* __restrict__ tr,
    const float* __restrict__ gw, const float* __restrict__ gb,
    float* __restrict__ nb_t1) {
  __shared__ float in[320];
  int e = blockIdx.x, t = threadIdx.x;
  in[t] = diag_T[e * 64 + t]; in[64 + t] = row_T[e * 64 + t];
  in[128 + t] = col_T[e * 64 + t]; in[192 + t] = tot[t]; in[256 + t] = tr[t];
  __syncthreads();
  float a = gb[t];
  for (int k = 0; k < 320; ++k) a += in[k] * gw[k * 64 + t];
  nb_t1[e * 64 + t] = a;
}

// ----- K17: coord weight w_e, seg/cnt/nb_t0 scatters, edge_attr passthrough --
__global__ __launch_bounds__(128) void k_edge_out(
    const int* __restrict__ edges, const float* __restrict__ coord_diff,
    const float* __restrict__ nb_t1, const float* __restrict__ edge_attr,
    const float* __restrict__ cw1, const float* __restrict__ cb1,
    const float* __restrict__ cw2,
    float* __restrict__ seg, float* __restrict__ cnt, float* __restrict__ nb_t0,
    float* __restrict__ out_ea) {
  __shared__ float in[64];
  __shared__ float red[128];
  int e = blockIdx.x, t = threadIdx.x;
  if (t < 64) in[t] = nb_t1[e * 64 + t];
  __syncthreads();
  float a = cb1[t];
  for (int k = 0; k < 64; ++k) a += in[k] * cw1[k * 128 + t];
  red[t] = silu_f(a) * cw2[t];
  __syncthreads();
  for (int s2 = 64; s2 > 0; s2 >>= 1) {
    if (t < s2) red[t] += red[t + s2];
    __syncthreads();
  }
  float w = red[0];
  int r = edges[e];
  if (t < 3) atomicAdd(&seg[r * 3 + t], coord_diff[e * 3 + t] * w);
  if (t == 64) atomicAdd(&cnt[r], 1.0f);
  if (t < 64) atomicAdd(&nb_t0[r * 64 + t], in[t]);
  if (t < 4) out_ea[e * 4 + t] = edge_attr[e * 4 + t];
}

// ---------------- K18: x_new and h_new ---------------------------------------
__global__ __launch_bounds__(128) void k_node_out(
    const float* __restrict__ h, const float* __restrict__ x,
    const float* __restrict__ seg, const float* __restrict__ cnt,
    const float* __restrict__ nb_t0,
    const float* __restrict__ w1, const float* __restrict__ b1,
    const float* __restrict__ w2, const float* __restrict__ b2,
    float* __restrict__ out_h, float* __restrict__ out_x) {
  __shared__ float in[64];
  __shared__ float hs[128];
  int n = blockIdx.x, t = threadIdx.x;
  if (t < 3) {
    float c = cnt[n]; if (c < 1.f) c = 1.f;
    out_x[n * 3 + t] = x[n * 3 + t] + seg[n * 3 + t] / c;
  }
  if (t < 64) in[t] = nb_t0[n * 64 + t];
  __syncthreads();
  float a = b1[t];
  for (int k = 0; k < 64; ++k) a += in[k] * w1[k * 128 + t];
  hs[t] = silu_f(a);
  __syncthreads();
  if (t < 64) {
    float o = b2[t];
    for (int k = 0; k < 128; ++k) o += hs[k] * w2[k * 64 + t];
    out_h[n * 64 + t] = h[n * 64 + t] + o;
  }
}

extern "C" void kernel_launch(void* const* d_in, const int* in_sizes, int n_in,
                              void* d_out, int out_size, void* d_ws, size_t ws_size,
                              hipStream_t stream) {
  (void)in_sizes; (void)n_in; (void)out_size; (void)ws_size;
  const float* h  = (const float*)d_in[0];
  const float* x  = (const float*)d_in[1];
  const int* edges   = (const int*)d_in[2];
  const int* nb_edge = (const int*)d_in[3];
  const float* edge_attr = (const float*)d_in[4];
  const float* ew1 = (const float*)d_in[6],  *eb1 = (const float*)d_in[7];
  const float* ew2 = (const float*)d_in[8],  *eb2 = (const float*)d_in[9];
  const float* p1w1 = (const float*)d_in[10], *p1b1 = (const float*)d_in[11];
  const float* p1w2 = (const float*)d_in[12], *p1b2 = (const float*)d_in[13];
  const float* p2w1 = (const float*)d_in[14], *p2b1 = (const float*)d_in[15];
  const float* p2w2 = (const float*)d_in[16], *p2b2 = (const float*)d_in[17];
  const float* p3w1 = (const float*)d_in[18], *p3b1 = (const float*)d_in[19];
  const float* p3w2 = (const float*)d_in[20], *p3b2 = (const float*)d_in[21];
  const float* ignw = (const float*)d_in[22], *ignb = (const float*)d_in[23];
  const float* cw1 = (const float*)d_in[24], *cb1 = (const float*)d_in[25];
  const float* cw2 = (const float*)d_in[26];
  const float* ndw1 = (const float*)d_in[27], *ndb1 = (const float*)d_in[28];
  const float* ndw2 = (const float*)d_in[29], *ndb2 = (const float*)d_in[30];

  // ---- workspace layout (~144 MB) ----
  char* ws = (char*)d_ws;
  __hip_bfloat16* S = (__hip_bfloat16*)(ws + 0);   // [262144][64] bf16 = 33,554,432 B
  float* row_part = (float*)(ws + 33554432);       // [64][512][128] = 16,777,216 B
  float* col_part = (float*)(ws + 50331648);       // 16,777,216 B
  // ---- single zero-memset block [67,108,864 .. 73,803,792) ----
  float* Tc    = (float*)(ws + 67108864);          // [16384][96] = 6,291,456 B
  int*   cntA  = (int*)(ws + 73400320);            // 512 ints
  int*   nC    = (int*)(ws + 73402368);            // 1 int (+pad)
  float* A     = (float*)(ws + 73402384);          // 32768 floats
  float* B     = (float*)(ws + 73533456);          // 32768 floats
  float* seg   = (float*)(ws + 73664528);          // 1536 floats
  float* cnt   = (float*)(ws + 73670672);          // 512 floats
  float* nb_t0 = (float*)(ws + 73672720);          // 32768 floats -> end 73,803,792
  // ---- rest ----
  int*   slotmap = (int*)(ws + 73803792);          // 262144 ints (memset 0xFF)
  int*   cells   = (int*)(ws + 74852368);          // 16384 ints
  int*   offA    = (int*)(ws + 74917904);          // 512 ints
  int*   curA    = (int*)(ws + 74919952);          // 512 ints
  int*   listAJ  = (int*)(ws + 74922000);          // 16384 ints
  float* D1      = (float*)(ws + 74987536);        // [16384][64]
  float* D2      = (float*)(ws + 79181840);        // [16384][64]
  float* TWc     = (float*)(ws + 83376144);        // [16384][128]
  float* c1      = (float*)(ws + 91764752);        // 64
  float* c2      = (float*)(ws + 91765008);        // 64
  float* u       = (float*)(ws + 91765264);        // [512][128]
  float* v       = (float*)(ws + 92027408);        // [512][128]
  float* coord_diff  = (float*)(ws + 92289552);    // [512][3]
  float* efn         = (float*)(ws + 92295696);    // [512][64]
  float* diag_silu   = (float*)(ws + 92426768);    // [512][128]
  float* rowsum_silu = (float*)(ws + 92688912);
  float* colsum_silu = (float*)(ws + 92951056);
  float* diag_T      = (float*)(ws + 93213200);    // [512][64]
  float* row_T       = (float*)(ws + 93344272);
  float* col_T       = (float*)(ws + 93475344);
  float* tot         = (float*)(ws + 93606416);    // 64
  float* tr          = (float*)(ws + 93606672);    // 64
  float* nb_t1       = (float*)(ws + 93606928);    // [512][64] -> end 93,738,000
  __hip_bfloat16* Wt = (__hip_bfloat16*)(ws + 93738000);  // [128][64] bf16 -> 93,754,384
  // ---- bucketed pair-list structures ----
  int*   cnt8   = (int*)(ws + 93754384);           // 4096 ints (memset 0)
  int*   off8   = (int*)(ws + 93770768);           // 4096
  int*   cur8   = (int*)(ws + 93787152);           // 4096
  int*   listS8 = (int*)(ws + 93803536);           // 16384 ints
  int*   pc     = (int*)(ws + 93869072);           // 4096
  int*   pOff2  = (int*)(ws + 93885456);           // 4096
  int*   cur2   = (int*)(ws + 93901840);           // 4096
  uint2* pairBuf = (uint2*)(ws + 93918224);        // PCAP2*8 = 48 MB -> 144,249,872

  float* out_h  = (float*)d_out;
  float* out_x  = out_h + 512 * 64;
  float* out_ea = out_x + 512 * 3;

  hipMemsetAsync(slotmap, 0xFF, 1048576, stream);          // -1
  hipMemsetAsync(ws + 67108864, 0, 6694928, stream);       // Tc..nb_t0
  hipMemsetAsync(cnt8, 0, 16384, stream);

  k_edge<<<512, 128, 0, stream>>>(h, x, edges, ew1, eb1, ew2, eb2, coord_diff, efn);
  k_consts<<<1, 128, 0, stream>>>(p1b1, p1w2, p1b2, p2b1, p2w2, p2b2, c1, c2);
  k_prep<<<32, 256, 0, stream>>>(p3w1, Wt);
  k_mark<<<64, 256, 0, stream>>>(nb_edge, slotmap);
  k_compact<<<1024, 256, 0, stream>>>(slotmap, cells, nC, cntA, cnt8);
  k_scan<<<1, 512, 0, stream>>>(cntA, offA, curA);
  k_fill<<<64, 256, 0, stream>>>(cells, nC, curA, listAJ);
  k_scan4096<<<1, 1024, 0, stream>>>(cnt8, off8, cur8);
  k_fill8<<<64, 256, 0, stream>>>(cells, nC, cur8, listS8);
  k_pcnt<<<512, 64, 0, stream>>>(cntA, offA, listAJ, cnt8, pc);
  k_scan4096<<<1, 1024, 0, stream>>>(pc, pOff2, cur2);
  k_pfill2<<<16384, 64, 0, stream>>>(nC, cells, listAJ, cnt8, off8, listS8, cur2, pairBuf);
  k_scatterT<<<8192, 192, 0, stream>>>(nb_edge, slotmap, coord_diff, efn, Tc);
  k_mlp96b<<<2048, 128, 0, stream>>>(cells, nC, Tc,
                                     p1w1, p1b1, p1w2, p1b2,
                                     p2w1, p2b1, p2w2, p2b2,
                                     c1, c2, p3w1, D1, D2, A, B, TWc);
  k_uv<<<dim3(512, 2), 128, 0, stream>>>(A, B, c1, c2, p3w1, p3b1, u, v);
  k_spmm<<<dim3(512, 2), 256, 0, stream>>>(pOff2, pc, pairBuf, D1, D2, S);
  k_tout_mfma<<<4096, 256, 0, stream>>>(S, u, v, TWc, slotmap, Wt,
                                        row_part, col_part, diag_silu);
  k_sumparts<<<512, 256, 0, stream>>>(row_part, col_part, rowsum_silu, colsum_silu);
  k_tout2<<<dim3(512, 3), 64, 0, stream>>>(diag_silu, rowsum_silu, colsum_silu,
                                           p3w2, p3b2, diag_T, row_T, col_T);
  k_totr<<<1, 128, 0, stream>>>(row_T, diag_T, tot, tr);
  k_nbt1<<<512, 64, 0, stream>>>(diag_T, row_T, col_T, tot, tr, ignw, ignb, nb_t1);
  k_edge_out<<<512, 128, 0, stream>>>(edges, coord_diff, nb_t1, edge_attr,
                                      cw1, cb1, cw2, seg, cnt, nb_t0, out_ea);
  k_node_out<<<512, 128, 0, stream>>>(h, x, seg, cnt, nb_t0,
                                      ndw1, ndb1, ndw2, ndb2, out_h, out_x);
}

// Round 9
// 477.828 us; speedup vs baseline: 1.0570x; 1.0570x over previous
//
#include <hip/hip_runtime.h>
#include <hip/hip_bf16.h>

// Problem constants (static per reference)
#define NN   512    // nodes
#define EE   512    // edges == nb-graph nodes (En)
#define MM   16384  // nb-graph edges
#define PCAP2 6291456  // pair-buffer capacity (actual ~524K)

typedef float v4f __attribute__((ext_vector_type(4)));
typedef short short8v __attribute__((ext_vector_type(8)));

__device__ __forceinline__ float silu_f(float v) { return v / (1.0f + __expf(-v)); }

// ---------------- K1: per original edge: coord_diff + efn = MLP([h_r|h_c]) ----
__global__ __launch_bounds__(128) void k_edge(
    const float* __restrict__ h, const float* __restrict__ x,
    const int* __restrict__ edges,
    const float* __restrict__ ew1, const float* __restrict__ eb1,
    const float* __restrict__ ew2, const float* __restrict__ eb2,
    float* __restrict__ coord_diff, float* __restrict__ efn) {
  __shared__ float hin[128];
  __shared__ float hs[128];
  int e = blockIdx.x;
  int t = threadIdx.x;
  int r = edges[e], c = edges[EE + e];
  if (t < 3) coord_diff[e * 3 + t] = x[r * 3 + t] - x[c * 3 + t];
  if (t < 64) { hin[t] = h[r * 64 + t]; hin[64 + t] = h[c * 64 + t]; }
  __syncthreads();
  float acc = eb1[t];
  for (int k = 0; k < 128; ++k) acc += hin[k] * ew1[k * 128 + t];
  hs[t] = silu_f(acc);
  __syncthreads();
  if (t < 64) {
    float o = eb2[t];
    for (int k = 0; k < 128; ++k) o += hs[k] * ew2[k * 64 + t];
    efn[e * 64 + t] = o;
  }
}

// ---------------- K2: constants c1 = MLP1(0), c2 = MLP2(0) -------------------
__global__ __launch_bounds__(128) void k_consts(
    const float* __restrict__ p1b1, const float* __restrict__ p1w2, const float* __restrict__ p1b2,
    const float* __restrict__ p2b1, const float* __restrict__ p2w2, const float* __restrict__ p2b2,
    float* __restrict__ c1, float* __restrict__ c2) {
  __shared__ float h1[128], h2[128];
  int t = threadIdx.x;
  h1[t] = silu_f(p1b1[t]); h2[t] = silu_f(p2b1[t]);
  __syncthreads();
  if (t < 64) {
    float a1 = p1b2[t], a2 = p2b2[t];
    for (int k = 0; k < 128; ++k) { a1 += h1[k] * p1w2[k * 64 + t]; a2 += h2[k] * p2w2[k * 64 + t]; }
    c1[t] = a1; c2[t] = a2;
  }
}

// ---------------- K2b: Wt[h][f] = bf16(p3w1[96+f][h]) (B-operand for MFMA) ---
__global__ __launch_bounds__(256) void k_prep(const float* __restrict__ p3w1,
                                              __hip_bfloat16* __restrict__ Wt) {
  int e = blockIdx.x * 256 + threadIdx.x;   // 8192 = 128 h x 64 f
  int hh = e >> 6, f = e & 63;
  Wt[hh * 64 + f] = __float2bfloat16(p3w1[(96 + f) * 128 + hh]);
}

// ---------------- K3: mark touched cells -------------------------------------
__global__ __launch_bounds__(256) void k_mark(const int* __restrict__ nb_edge,
                                              int* __restrict__ slotmap) {
  int m = blockIdx.x * 256 + threadIdx.x;
  if (m >= MM) return;
  int cell = nb_edge[m] * 512 + nb_edge[MM + m];
  atomicCAS(&slotmap[cell], -1, -2);
}

// ------ K4: compact marked cells -> slots, row histogram + bucket histogram --
__global__ __launch_bounds__(256) void k_compact(int* __restrict__ slotmap,
                                                 int* __restrict__ cells,
                                                 int* __restrict__ nC,
                                                 int* __restrict__ cntA,
                                                 int* __restrict__ cnt8) {
  int cell = blockIdx.x * 256 + threadIdx.x;
  if (slotmap[cell] != -2) return;
  int s = atomicAdd(nC, 1);
  slotmap[cell] = s;
  cells[s] = cell;
  atomicAdd(&cntA[cell >> 9], 1);                              // by first coord a
  atomicAdd(&cnt8[(cell >> 9) * 8 + ((cell & 511) >> 6)], 1);  // by (a, j>>6)
}

// ---------------- K5: prefix sum for the row CSR -----------------------------
__global__ __launch_bounds__(512) void k_scan(const int* __restrict__ cntA,
                                              int* __restrict__ offA,
                                              int* __restrict__ curA) {
  __shared__ int sA[512];
  int t = threadIdx.x;
  int a0 = cntA[t];
  sA[t] = a0;
  for (int off = 1; off < 512; off <<= 1) {
    __syncthreads();
    int a = (t >= off) ? sA[t - off] : 0;
    __syncthreads();
    sA[t] += a;
  }
  __syncthreads();
  offA[t] = sA[t] - a0;
  curA[t] = sA[t] - a0;
}

// ---------------- K5b: generic 4096-element exclusive scan -------------------
__global__ __launch_bounds__(1024) void k_scan4096(
    const int* __restrict__ cntIn, int* __restrict__ offOut, int* __restrict__ curOut) {
  __shared__ int part[1024];
  int t = threadIdx.x;
  int v[4]; int sum = 0;
#pragma unroll
  for (int ii = 0; ii < 4; ++ii) { v[ii] = cntIn[t * 4 + ii]; sum += v[ii]; }
  part[t] = sum;
  for (int off = 1; off < 1024; off <<= 1) {
    __syncthreads();
    int a = (t >= off) ? part[t - off] : 0;
    __syncthreads();
    part[t] += a;
  }
  __syncthreads();
  int r = part[t] - sum;
#pragma unroll
  for (int ii = 0; ii < 4; ++ii) {
    offOut[t * 4 + ii] = r; curOut[t * 4 + ii] = r; r += v[ii];
  }
}

// -------- K6: fill row CSR list, packing slot | (second-coord << 18) ---------
__global__ __launch_bounds__(256) void k_fill(const int* __restrict__ cells, const int* __restrict__ nC,
                                              int* __restrict__ curA,
                                              int* __restrict__ listAJ) {
  int s = blockIdx.x * 256 + threadIdx.x;
  if (s >= *nC) return;
  int cell = cells[s];
  listAJ[atomicAdd(&curA[cell >> 9], 1)] = s | ((cell & 511) << 18);
}

// -------- K6b: fill bucketed cell list, packing slot | (j&63)<<18 ------------
__global__ __launch_bounds__(256) void k_fill8(const int* __restrict__ cells, const int* __restrict__ nC,
                                               int* __restrict__ cur8,
                                               int* __restrict__ listS8) {
  int s = blockIdx.x * 256 + threadIdx.x;
  if (s >= *nC) return;
  int cell = cells[s];
  int a = cell >> 9, b = cell & 511;
  listS8[atomicAdd(&cur8[a * 8 + (b >> 6)], 1)] = s | ((b & 63) << 18);
}

// -------- K6c: pair counts per (row i, jr): pc = sum over row cells of cnt8 --
__global__ __launch_bounds__(64) void k_pcnt(
    const int* __restrict__ cntA, const int* __restrict__ offA,
    const int* __restrict__ listAJ, const int* __restrict__ cnt8,
    int* __restrict__ pc) {
  __shared__ int acc[64];
  int i = blockIdx.x, t = threadIdx.x;
  int jr = t & 7, par = t >> 3;
  int n1 = cntA[i], o1 = offA[i];
  int s = 0;
  for (int q = par; q < n1; q += 8) {
    int k = listAJ[o1 + q] >> 18;
    s += cnt8[k * 8 + jr];
  }
  acc[t] = s;
  __syncthreads();
  if (t < 8) {
    int tot = 0;
    for (int pp = 0; pp < 8; ++pp) tot += acc[pp * 8 + t];
    pc[i * 8 + t] = tot;
  }
}

// -------- K6d: fill flat pair buffer, bucketed by (row i, jr); 4 cells/block -
__global__ __launch_bounds__(256) void k_pfill2(
    const int* __restrict__ nC, const int* __restrict__ cells,
    const int* __restrict__ listAJ,
    const int* __restrict__ cnt8, const int* __restrict__ off8,
    const int* __restrict__ listS8,
    int* __restrict__ cur2, uint2* __restrict__ pairBuf) {
  __shared__ int baseS[4][8];
  int grp = threadIdx.x >> 6, lane = threadIdx.x & 63;
  int q = blockIdx.x * 4 + grp;
  int nc = *nC;
  bool act = (q < nc);
  int s1 = 0, k = 0, i = 0;
  if (act) {
    int e1 = listAJ[q];
    s1 = e1 & 0x3FFFF;
    k = e1 >> 18;
    i = cells[s1] >> 9;
  }
  if (act && lane < 8) {
    int nn = cnt8[k * 8 + lane];
    baseS[grp][lane] = nn ? atomicAdd(&cur2[i * 8 + lane], nn) : 0;
  }
  __syncthreads();
  if (act) {
    for (int jr = 0; jr < 8; ++jr) {
      int nn = cnt8[k * 8 + jr], oo = off8[k * 8 + jr], bb = baseS[grp][jr];
      for (int e = lane; e < nn; e += 64)
        if (bb + e < PCAP2)
          pairBuf[bb + e] = make_uint2((unsigned)s1, (unsigned)listS8[oo + e]);
    }
  }
}

// ---------------- K7: nb_feat scatter-add into COMPACT Tc (2 edges/block) ----
__global__ __launch_bounds__(192) void k_scatterT(
    const int* __restrict__ nb_edge, const int* __restrict__ slotmap,
    const float* __restrict__ coord_diff, const float* __restrict__ efn,
    float* __restrict__ Tc) {
  int t = threadIdx.x;
  int sub = (t >= 96) ? 1 : 0;
  int c = t - sub * 96;
  int m = blockIdx.x * 2 + sub;
  int a = nb_edge[m], b = nb_edge[MM + m];
  int s = slotmap[a * 512 + b];
  float val;
  if (c < 32) {
    float vtv = coord_diff[a * 3 + 0] * coord_diff[b * 3 + 0]
              + coord_diff[a * 3 + 1] * coord_diff[b * 3 + 1]
              + coord_diff[a * 3 + 2] * coord_diff[b * 3 + 2];
    int i = c >> 1;
    float ang = vtv * 16.0f * __expf(-0.57564627324851143f * (float)i);
    val = (c & 1) ? cosf(ang) : sinf(ang);
  } else {
    int f = c - 32;
    val = efn[a * 64 + f] * efn[b * 64 + f];
  }
  atomicAdd(&Tc[s * 96 + c], val);
}

// ------- K8: batched (8 cells/block) MLPs -> D1/D2, sums A,B; TWc = Tc@w1T ---
__global__ __launch_bounds__(128) void k_mlp96b(
    const int* __restrict__ cells, const int* __restrict__ nC, const float* __restrict__ Tc,
    const float* __restrict__ w11, const float* __restrict__ b11,
    const float* __restrict__ w12, const float* __restrict__ b12,
    const float* __restrict__ w21, const float* __restrict__ b21,
    const float* __restrict__ w22, const float* __restrict__ b22,
    const float* __restrict__ c1, const float* __restrict__ c2,
    const float* __restrict__ p3w1,
    float* __restrict__ D1, float* __restrict__ D2,
    float* __restrict__ A, float* __restrict__ B,
    float* __restrict__ TWc) {
  __shared__ float xsT[96 * 8];    // [k][cell] transposed for b128 reads
  __shared__ float hid[8][128];
  __shared__ int cl[8];
  int t = threadIdx.x;
  int nc = *nC;
  int s0 = blockIdx.x * 8;
  if (s0 >= nc) return;
  for (int e = t; e < 768; e += 128) xsT[(e % 96) * 8 + e / 96] = Tc[s0 * 96 + e];
  if (t < 8) cl[t] = (s0 + t < nc) ? cells[s0 + t] : 0;
  __syncthreads();
  float tw[8], a1[8], a2[8];
#pragma unroll
  for (int c = 0; c < 8; ++c) { tw[c] = 0.f; a1[c] = b11[t]; a2[c] = b21[t]; }
  for (int k = 0; k < 96; ++k) {
    float wt = p3w1[k * 128 + t];
    float w1v = w11[k * 128 + t];
    float w2v = w21[k * 128 + t];
    float4 xlo = *(const float4*)&xsT[k * 8];
    float4 xhi = *(const float4*)&xsT[k * 8 + 4];
    float xv[8] = {xlo.x, xlo.y, xlo.z, xlo.w, xhi.x, xhi.y, xhi.z, xhi.w};
#pragma unroll
    for (int c = 0; c < 8; ++c) {
      tw[c] += xv[c] * wt; a1[c] += xv[c] * w1v; a2[c] += xv[c] * w2v;
    }
  }
#pragma unroll
  for (int c = 0; c < 8; ++c) {
    if (s0 + c < nc) TWc[(s0 + c) * 128 + t] = tw[c];
    hid[c][t] = silu_f(a1[c]);
  }
  __syncthreads();
  {
    int hh = t & 63, cq = t >> 6;
    float o[4];
#pragma unroll
    for (int cc = 0; cc < 4; ++cc) o[cc] = b12[hh];
    for (int k = 0; k < 128; ++k) {
      float w = w12[k * 64 + hh];
#pragma unroll
      for (int cc = 0; cc < 4; ++cc) o[cc] += hid[cq * 4 + cc][k] * w;
    }
#pragma unroll
    for (int cc = 0; cc < 4; ++cc) {
      int c = cq * 4 + cc;
      if (s0 + c < nc) {
        float d = o[cc] - c1[hh];
        D1[(s0 + c) * 64 + hh] = d;
        atomicAdd(&A[(cl[c] >> 9) * 64 + hh], d);
      }
    }
  }
  __syncthreads();
#pragma unroll
  for (int c = 0; c < 8; ++c) hid[c][t] = silu_f(a2[c]);
  __syncthreads();
  {
    int hh = t & 63, cq = t >> 6;
    float o[4];
#pragma unroll
    for (int cc = 0; cc < 4; ++cc) o[cc] = b22[hh];
    for (int k = 0; k < 128; ++k) {
      float w = w22[k * 64 + hh];
#pragma unroll
      for (int cc = 0; cc < 4; ++cc) o[cc] += hid[cq * 4 + cc][k] * w;
    }
#pragma unroll
    for (int cc = 0; cc < 4; ++cc) {
      int c = cq * 4 + cc;
      if (s0 + c < nc) {
        float d = o[cc] - c2[hh];
        D2[(s0 + c) * 64 + hh] = d;
        atomicAdd(&B[(cl[c] & 511) * 64 + hh], d);
      }
    }
  }
}

// ---------------- K10: u[i] = b1 + (512 c1c2 + c2*A[i])@w1m ; v[j] = (c1*B[j])@w1m
__global__ __launch_bounds__(128) void k_uv(
    const float* __restrict__ A, const float* __restrict__ B,
    const float* __restrict__ c1, const float* __restrict__ c2,
    const float* __restrict__ p3w1, const float* __restrict__ p3b1,
    float* __restrict__ u, float* __restrict__ v) {
  __shared__ float vec[64];
  int i = blockIdx.x, y = blockIdx.y, t = threadIdx.x;
  if (t < 64)
    vec[t] = (y == 0) ? (512.0f * c1[t] * c2[t] + c2[t] * A[i * 64 + t])
                      : (c1[t] * B[i * 64 + t]);
  __syncthreads();
  float a = (y == 0) ? p3b1[t] : 0.f;
  for (int f = 0; f < 64; ++f) a += vec[f] * p3w1[(96 + f) * 128 + t];
  (y == 0 ? u : v)[i * 128 + t] = a;
}

// ---------------- K11: S accumulation, wave-private j-slabs, CHUNK-PIPELINED -
// Grid (512 rows, 2); block 256 = 4 waves; wave owns a 64-j slab (f = lane).
// Chunks of 8 pairs: entries held 2 chunks ahead, D-rows for chunk c+1 issued
// BEFORE the RMWs of chunk c -> ~24 independent loads in flight per wave.
// No atomics, no barriers; same-j RAW ordered by the in-order LDS pipe.
#define CH 8
__global__ __launch_bounds__(256) void k_spmm(
    const int* __restrict__ pOff2, const int* __restrict__ pc,
    const uint2* __restrict__ pairBuf,
    const float* __restrict__ D1, const float* __restrict__ D2,
    __hip_bfloat16* __restrict__ S) {
  __shared__ float slabs[4][4096];   // 64 KB
  int i = blockIdx.x;
  int w = threadIdx.x >> 6, lane = threadIdx.x & 63;
  int jr = blockIdx.y * 4 + w;
  float* slab = slabs[w];
  for (int e = lane; e < 4096; e += 64) slab[e] = 0.f;
  int n = pc[i * 8 + jr], base = pOff2[i * 8 + jr];
  uint2 eb0[CH], eb1[CH];
  float d1b[CH], d2b[CH];
#pragma unroll
  for (int c = 0; c < CH; ++c)
    eb0[c] = (c < n) ? pairBuf[base + c] : make_uint2(0u, 0u);
#pragma unroll
  for (int c = 0; c < CH; ++c)
    eb1[c] = (CH + c < n) ? pairBuf[base + CH + c] : make_uint2(0u, 0u);
#pragma unroll
  for (int c = 0; c < CH; ++c) {
    bool vv = (c < n);
    d1b[c] = vv ? D1[eb0[c].x * 64 + lane] : 0.f;
    d2b[c] = vv ? D2[(eb0[c].y & 0x3FFFFu) * 64 + lane] : 0.f;
  }
  for (int p0 = 0; p0 < n; p0 += CH) {
    // stage 1: D-rows for chunk c+1 (entries already resident in eb1)
    float d1n[CH], d2n[CH];
#pragma unroll
    for (int c = 0; c < CH; ++c) {
      bool vv = (p0 + CH + c < n);
      d1n[c] = vv ? D1[eb1[c].x * 64 + lane] : 0.f;
      d2n[c] = vv ? D2[(eb1[c].y & 0x3FFFFu) * 64 + lane] : 0.f;
    }
    // stage 2: entries for chunk c+2
    uint2 eb2[CH];
#pragma unroll
    for (int c = 0; c < CH; ++c) {
      int idx = p0 + 2 * CH + c;
      eb2[c] = (idx < n) ? pairBuf[base + idx] : make_uint2(0u, 0u);
    }
    // stage 3: RMW current chunk (data already in registers)
#pragma unroll
    for (int c = 0; c < CH; ++c) {
      if (p0 + c < n) {
        int jloc = eb0[c].y >> 18;
        slab[jloc * 64 + lane] += d1b[c] * d2b[c];
      }
    }
#pragma unroll
    for (int c = 0; c < CH; ++c) {
      eb0[c] = eb1[c]; eb1[c] = eb2[c]; d1b[c] = d1n[c]; d2b[c] = d2n[c];
    }
  }
  int j0 = jr * 64;
  for (int jl = 0; jl < 64; ++jl)
    S[(i * 512 + j0 + jl) * 64 + lane] = __float2bfloat16(slab[jl * 64 + lane]);
}

// ------- K12: MFMA z = S@Wt + u[i]+v[j]+TW, silu, row/col/diag reduce --------
// Block = 8x8 cells (bi,bj); 4 waves; wave w owns cells w*16..w*16+15.
// C layout: h = n0+(lane&15), cell = w*16 + quad*4 + reg  [m89-verified].
__global__ __launch_bounds__(256) void k_tout_mfma(
    const __hip_bfloat16* __restrict__ S, const float* __restrict__ u,
    const float* __restrict__ v, const float* __restrict__ TWc,
    const int* __restrict__ slotmap, const __hip_bfloat16* __restrict__ Wt,
    float* __restrict__ row_part, float* __restrict__ col_part,
    float* __restrict__ diag_silu) {
  __shared__ __hip_bfloat16 WtL[128 * 72];   // 18,432 B (pad 72 -> 2-way banks)
  __shared__ float uvL[2048];                // u rows | v rows, 8 KB
  __shared__ float colbuf[4][8][128];        // 16 KB
  __shared__ int slotL[64];
  int t = threadIdx.x;
  int w = t >> 6, lane = t & 63;
  int q = lane >> 4, l15 = lane & 15;
  int bi = blockIdx.x >> 6, bj = blockIdx.x & 63;
  int i0 = bi * 8, j0 = bj * 8;
  for (int e = t; e < 4096; e += 256) {
    int row = e >> 5, c2 = e & 31;
    ((unsigned*)WtL)[row * 36 + c2] = ((const unsigned*)Wt)[row * 32 + c2];
  }
  for (int e = t; e < 1024; e += 256) uvL[e] = u[(i0 + (e >> 7)) * 128 + (e & 127)];
  for (int e = t; e < 1024; e += 256) uvL[1024 + e] = v[(j0 + (e >> 7)) * 128 + (e & 127)];
  if (t < 64) slotL[t] = slotmap[(i0 + (t >> 3)) * 512 + j0 + (t & 7)];
  int cellA = w * 16 + l15;
  const short8v* sp = (const short8v*)&S[((i0 + (cellA >> 3)) * 512 + j0 + (cellA & 7)) * 64];
  short8v a0 = sp[q];
  short8v a1 = sp[4 + q];
  __syncthreads();
  v4f acc[8];
#pragma unroll
  for (int nt = 0; nt < 8; ++nt) {
    const short8v* b0 = (const short8v*)&WtL[(nt * 16 + l15) * 72 + q * 8];
    const short8v* b1 = (const short8v*)&WtL[(nt * 16 + l15) * 72 + 32 + q * 8];
    v4f c = {0.f, 0.f, 0.f, 0.f};
    c = __builtin_amdgcn_mfma_f32_16x16x32_bf16(a0, *b0, c, 0, 0, 0);
    c = __builtin_amdgcn_mfma_f32_16x16x32_bf16(a1, *b1, c, 0, 0, 0);
    acc[nt] = c;
  }
  float colp[8][4];
#pragma unroll
  for (int nt = 0; nt < 8; ++nt) {
    int hh = nt * 16 + l15;
    float rsum = 0.f;
#pragma unroll
    for (int r = 0; r < 4; ++r) {
      int c = w * 16 + q * 4 + r;
      int iL = c >> 3, jL = c & 7;
      float z = acc[nt][r] + uvL[iL * 128 + hh] + uvL[1024 + jL * 128 + hh];
      int s = slotL[c];
      if (s >= 0) z += TWc[s * 128 + hh];
      float sv = silu_f(z);
      rsum += sv;
      colp[nt][r] = sv + __shfl_xor(sv, 32);
      if (bi == bj && iL == jL) diag_silu[(i0 + iL) * 128 + hh] = sv;
    }
    rsum += __shfl_xor(rsum, 16);
    if ((q & 1) == 0)
      row_part[(bj * 512 + i0 + 2 * w + (q >> 1)) * 128 + hh] = rsum;
  }
  if (q < 2) {
#pragma unroll
    for (int nt = 0; nt < 8; ++nt)
#pragma unroll
      for (int r = 0; r < 4; ++r)
        colbuf[w][q * 4 + r][nt * 16 + l15] = colp[nt][r];
  }
  __syncthreads();
  for (int e = t; e < 1024; e += 256) {
    int jL = e >> 7, hh = e & 127;
    float a = colbuf[0][jL][hh] + colbuf[1][jL][hh] + colbuf[2][jL][hh] + colbuf[3][jL][hh];
    col_part[(bi * 512 + j0 + jL) * 128 + hh] = a;
  }
}

// ---------------- K13: reduce 64 partial slices ------------------------------
__global__ __launch_bounds__(256) void k_sumparts(
    const float* __restrict__ row_part, const float* __restrict__ col_part,
    float* __restrict__ rowsum, float* __restrict__ colsum) {
  int i = blockIdx.x, t = threadIdx.x;
  const float* src = (t < 128) ? row_part : col_part;
  float* dst = (t < 128) ? rowsum : colsum;
  int hc = t & 127;
  float a = 0.f;
  for (int p = 0; p < 64; ++p) a += src[(p * 512 + i) * 128 + hc];
  dst[i * 128 + hc] = a;
}

// ---------------- K14: second layer of p3 MLP on reduced silu sums -----------
__global__ __launch_bounds__(64) void k_tout2(
    const float* __restrict__ diag_silu, const float* __restrict__ rowsum_silu,
    const float* __restrict__ colsum_silu,
    const float* __restrict__ w2, const float* __restrict__ b2,
    float* __restrict__ diag_T, float* __restrict__ row_T, float* __restrict__ col_T) {
  __shared__ float in[128];
  int e = blockIdx.x, which = blockIdx.y, t = threadIdx.x;
  const float* src = (which == 0) ? diag_silu : (which == 1) ? rowsum_silu : colsum_silu;
  in[t] = src[e * 128 + t]; in[64 + t] = src[e * 128 + 64 + t];
  __syncthreads();
  float a = 0.f;
  for (int k = 0; k < 128; ++k) a += in[k] * w2[k * 64 + t];
  float bias = b2[t] * ((which == 0) ? 1.0f : 512.0f);
  float* dst = (which == 0) ? diag_T : (which == 1) ? row_T : col_T;
  dst[e * 64 + t] = a + bias;
}

// ---------------- K15: tot / tr ----------------------------------------------
__global__ __launch_bounds__(128) void k_totr(
    const float* __restrict__ row_T, const float* __restrict__ diag_T,
    float* __restrict__ tot, float* __restrict__ tr) {
  int t = threadIdx.x;
  const float* src = (t < 64) ? row_T : diag_T;
  int f = t & 63;
  float a = 0.f;
  for (int e = 0; e < 512; ++e) a += src[e * 64 + f];
  if (t < 64) tot[f] = a; else tr[f] = a;
}

// ---------------- K16: nb_t1 = [diag|row|col|tot|tr] @ ign_w + ign_b ---------
__global__ __launch_bounds__(64) void k_nbt1(
    const float* __restrict__ diag_T, const float* __restrict__ row_T,
    const float* __restrict__ col_T, const float* __restrict__ tot,
    const float* __restrict__ tr,
    const float* __restrict__ gw, const float* __restrict__ gb,
    float* __restrict__ nb_t1) {
  __shared__ float in[320];
  int e = blockIdx.x, t = threadIdx.x;
  in[t] = diag_T[e * 64 + t]; in[64 + t] = row_T[e * 64 + t];
  in[128 + t] = col_T[e * 64 + t]; in[192 + t] = tot[t]; in[256 + t] = tr[t];
  __syncthreads();
  float a = gb[t];
  for (int k = 0; k < 320; ++k) a += in[k] * gw[k * 64 + t];
  nb_t1[e * 64 + t] = a;
}

// ----- K17: coord weight w_e, seg/cnt/nb_t0 scatters, edge_attr passthrough --
__global__ __launch_bounds__(128) void k_edge_out(
    const int* __restrict__ edges, const float* __restrict__ coord_diff,
    const float* __restrict__ nb_t1, const float* __restrict__ edge_attr,
    const float* __restrict__ cw1, const float* __restrict__ cb1,
    const float* __restrict__ cw2,
    float* __restrict__ seg, float* __restrict__ cnt, float* __restrict__ nb_t0,
    float* __restrict__ out_ea) {
  __shared__ float in[64];
  __shared__ float red[128];
  int e = blockIdx.x, t = threadIdx.x;
  if (t < 64) in[t] = nb_t1[e * 64 + t];
  __syncthreads();
  float a = cb1[t];
  for (int k = 0; k < 64; ++k) a += in[k] * cw1[k * 128 + t];
  red[t] = silu_f(a) * cw2[t];
  __syncthreads();
  for (int s2 = 64; s2 > 0; s2 >>= 1) {
    if (t < s2) red[t] += red[t + s2];
    __syncthreads();
  }
  float w = red[0];
  int r = edges[e];
  if (t < 3) atomicAdd(&seg[r * 3 + t], coord_diff[e * 3 + t] * w);
  if (t == 64) atomicAdd(&cnt[r], 1.0f);
  if (t < 64) atomicAdd(&nb_t0[r * 64 + t], in[t]);
  if (t < 4) out_ea[e * 4 + t] = edge_attr[e * 4 + t];
}

// ---------------- K18: x_new and h_new ---------------------------------------
__global__ __launch_bounds__(128) void k_node_out(
    const float* __restrict__ h, const float* __restrict__ x,
    const float* __restrict__ seg, const float* __restrict__ cnt,
    const float* __restrict__ nb_t0,
    const float* __restrict__ w1, const float* __restrict__ b1,
    const float* __restrict__ w2, const float* __restrict__ b2,
    float* __restrict__ out_h, float* __restrict__ out_x) {
  __shared__ float in[64];
  __shared__ float hs[128];
  int n = blockIdx.x, t = threadIdx.x;
  if (t < 3) {
    float c = cnt[n]; if (c < 1.f) c = 1.f;
    out_x[n * 3 + t] = x[n * 3 + t] + seg[n * 3 + t] / c;
  }
  if (t < 64) in[t] = nb_t0[n * 64 + t];
  __syncthreads();
  float a = b1[t];
  for (int k = 0; k < 64; ++k) a += in[k] * w1[k * 128 + t];
  hs[t] = silu_f(a);
  __syncthreads();
  if (t < 64) {
    float o = b2[t];
    for (int k = 0; k < 128; ++k) o += hs[k] * w2[k * 64 + t];
    out_h[n * 64 + t] = h[n * 64 + t] + o;
  }
}

extern "C" void kernel_launch(void* const* d_in, const int* in_sizes, int n_in,
                              void* d_out, int out_size, void* d_ws, size_t ws_size,
                              hipStream_t stream) {
  (void)in_sizes; (void)n_in; (void)out_size; (void)ws_size;
  const float* h  = (const float*)d_in[0];
  const float* x  = (const float*)d_in[1];
  const int* edges   = (const int*)d_in[2];
  const int* nb_edge = (const int*)d_in[3];
  const float* edge_attr = (const float*)d_in[4];
  const float* ew1 = (const float*)d_in[6],  *eb1 = (const float*)d_in[7];
  const float* ew2 = (const float*)d_in[8],  *eb2 = (const float*)d_in[9];
  const float* p1w1 = (const float*)d_in[10], *p1b1 = (const float*)d_in[11];
  const float* p1w2 = (const float*)d_in[12], *p1b2 = (const float*)d_in[13];
  const float* p2w1 = (const float*)d_in[14], *p2b1 = (const float*)d_in[15];
  const float* p2w2 = (const float*)d_in[16], *p2b2 = (const float*)d_in[17];
  const float* p3w1 = (const float*)d_in[18], *p3b1 = (const float*)d_in[19];
  const float* p3w2 = (const float*)d_in[20], *p3b2 = (const float*)d_in[21];
  const float* ignw = (const float*)d_in[22], *ignb = (const float*)d_in[23];
  const float* cw1 = (const float*)d_in[24], *cb1 = (const float*)d_in[25];
  const float* cw2 = (const float*)d_in[26];
  const float* ndw1 = (const float*)d_in[27], *ndb1 = (const float*)d_in[28];
  const float* ndw2 = (const float*)d_in[29], *ndb2 = (const float*)d_in[30];

  // ---- workspace layout (~144 MB) ----
  char* ws = (char*)d_ws;
  __hip_bfloat16* S = (__hip_bfloat16*)(ws + 0);   // [262144][64] bf16 = 33,554,432 B
  float* row_part = (float*)(ws + 33554432);       // [64][512][128] = 16,777,216 B
  float* col_part = (float*)(ws + 50331648);       // 16,777,216 B
  // ---- single zero-memset block [67,108,864 .. 73,803,792) ----
  float* Tc    = (float*)(ws + 67108864);          // [16384][96] = 6,291,456 B
  int*   cntA  = (int*)(ws + 73400320);            // 512 ints
  int*   nC    = (int*)(ws + 73402368);            // 1 int (+pad)
  float* A     = (float*)(ws + 73402384);          // 32768 floats
  float* B     = (float*)(ws + 73533456);          // 32768 floats
  float* seg   = (float*)(ws + 73664528);          // 1536 floats
  float* cnt   = (float*)(ws + 73670672);          // 512 floats
  float* nb_t0 = (float*)(ws + 73672720);          // 32768 floats -> end 73,803,792
  // ---- rest ----
  int*   slotmap = (int*)(ws + 73803792);          // 262144 ints (memset 0xFF)
  int*   cells   = (int*)(ws + 74852368);          // 16384 ints
  int*   offA    = (int*)(ws + 74917904);          // 512 ints
  int*   curA    = (int*)(ws + 74919952);          // 512 ints
  int*   listAJ  = (int*)(ws + 74922000);          // 16384 ints
  float* D1      = (float*)(ws + 74987536);        // [16384][64]
  float* D2      = (float*)(ws + 79181840);        // [16384][64]
  float* TWc     = (float*)(ws + 83376144);        // [16384][128]
  float* c1      = (float*)(ws + 91764752);        // 64
  float* c2      = (float*)(ws + 91765008);        // 64
  float* u       = (float*)(ws + 91765264);        // [512][128]
  float* v       = (float*)(ws + 92027408);        // [512][128]
  float* coord_diff  = (float*)(ws + 92289552);    // [512][3]
  float* efn         = (float*)(ws + 92295696);    // [512][64]
  float* diag_silu   = (float*)(ws + 92426768);    // [512][128]
  float* rowsum_silu = (float*)(ws + 92688912);
  float* colsum_silu = (float*)(ws + 92951056);
  float* diag_T      = (float*)(ws + 93213200);    // [512][64]
  float* row_T       = (float*)(ws + 93344272);
  float* col_T       = (float*)(ws + 93475344);
  float* tot         = (float*)(ws + 93606416);    // 64
  float* tr          = (float*)(ws + 93606672);    // 64
  float* nb_t1       = (float*)(ws + 93606928);    // [512][64] -> end 93,738,000
  __hip_bfloat16* Wt = (__hip_bfloat16*)(ws + 93738000);  // [128][64] bf16 -> 93,754,384
  // ---- bucketed pair-list structures ----
  int*   cnt8   = (int*)(ws + 93754384);           // 4096 ints (memset 0)
  int*   off8   = (int*)(ws + 93770768);           // 4096
  int*   cur8   = (int*)(ws + 93787152);           // 4096
  int*   listS8 = (int*)(ws + 93803536);           // 16384 ints
  int*   pc     = (int*)(ws + 93869072);           // 4096
  int*   pOff2  = (int*)(ws + 93885456);           // 4096
  int*   cur2   = (int*)(ws + 93901840);           // 4096
  uint2* pairBuf = (uint2*)(ws + 93918224);        // PCAP2*8 = 48 MB -> 144,249,872

  float* out_h  = (float*)d_out;
  float* out_x  = out_h + 512 * 64;
  float* out_ea = out_x + 512 * 3;

  hipMemsetAsync(slotmap, 0xFF, 1048576, stream);          // -1
  hipMemsetAsync(ws + 67108864, 0, 6694928, stream);       // Tc..nb_t0
  hipMemsetAsync(cnt8, 0, 16384, stream);

  k_edge<<<512, 128, 0, stream>>>(h, x, edges, ew1, eb1, ew2, eb2, coord_diff, efn);
  k_consts<<<1, 128, 0, stream>>>(p1b1, p1w2, p1b2, p2b1, p2w2, p2b2, c1, c2);
  k_prep<<<32, 256, 0, stream>>>(p3w1, Wt);
  k_mark<<<64, 256, 0, stream>>>(nb_edge, slotmap);
  k_compact<<<1024, 256, 0, stream>>>(slotmap, cells, nC, cntA, cnt8);
  k_scan<<<1, 512, 0, stream>>>(cntA, offA, curA);
  k_fill<<<64, 256, 0, stream>>>(cells, nC, curA, listAJ);
  k_scan4096<<<1, 1024, 0, stream>>>(cnt8, off8, cur8);
  k_fill8<<<64, 256, 0, stream>>>(cells, nC, cur8, listS8);
  k_pcnt<<<512, 64, 0, stream>>>(cntA, offA, listAJ, cnt8, pc);
  k_scan4096<<<1, 1024, 0, stream>>>(pc, pOff2, cur2);
  k_pfill2<<<4096, 256, 0, stream>>>(nC, cells, listAJ, cnt8, off8, listS8, cur2, pairBuf);
  k_scatterT<<<8192, 192, 0, stream>>>(nb_edge, slotmap, coord_diff, efn, Tc);
  k_mlp96b<<<2048, 128, 0, stream>>>(cells, nC, Tc,
                                     p1w1, p1b1, p1w2, p1b2,
                                     p2w1, p2b1, p2w2, p2b2,
                                     c1, c2, p3w1, D1, D2, A, B, TWc);
  k_uv<<<dim3(512, 2), 128, 0, stream>>>(A, B, c1, c2, p3w1, p3b1, u, v);
  k_spmm<<<dim3(512, 2), 256, 0, stream>>>(pOff2, pc, pairBuf, D1, D2, S);
  k_tout_mfma<<<4096, 256, 0, stream>>>(S, u, v, TWc, slotmap, Wt,
                                        row_part, col_part, diag_silu);
  k_sumparts<<<512, 256, 0, stream>>>(row_part, col_part, rowsum_silu, colsum_silu);
  k_tout2<<<dim3(512, 3), 64, 0, stream>>>(diag_silu, rowsum_silu, colsum_silu,
                                           p3w2, p3b2, diag_T, row_T, col_T);
  k_totr<<<1, 128, 0, stream>>>(row_T, diag_T, tot, tr);
  k_nbt1<<<512, 64, 0, stream>>>(diag_T, row_T, col_T, tot, tr, ignw, ignb, nb_t1);
  k_edge_out<<<512, 128, 0, stream>>>(edges, coord_diff, nb_t1, edge_attr,
                                      cw1, cb1, cw2, seg, cnt, nb_t0, out_ea);
  k_node_out<<<512, 128, 0, stream>>>(h, x, seg, cnt, nb_t0,
                                      ndw1, ndb1, ndw2, ndb2, out_h, out_x);
}

// Round 10
// 456.212 us; speedup vs baseline: 1.1071x; 1.0474x over previous
//
#include <hip/hip_runtime.h>
#include <hip/hip_bf16.h>

// Problem constants (static per reference)
#define NN   512    // nodes
#define EE   512    // edges == nb-graph nodes (En)
#define MM   16384  // nb-graph edges

typedef float v4f __attribute__((ext_vector_type(4)));
typedef short short8v __attribute__((ext_vector_type(8)));

__device__ __forceinline__ float silu_f(float v) { return v / (1.0f + __expf(-v)); }

// ---------------- K1: per original edge: coord_diff + efn = MLP([h_r|h_c]) ----
__global__ __launch_bounds__(128) void k_edge(
    const float* __restrict__ h, const float* __restrict__ x,
    const int* __restrict__ edges,
    const float* __restrict__ ew1, const float* __restrict__ eb1,
    const float* __restrict__ ew2, const float* __restrict__ eb2,
    float* __restrict__ coord_diff, float* __restrict__ efn) {
  __shared__ float hin[128];
  __shared__ float hs[128];
  int e = blockIdx.x;
  int t = threadIdx.x;
  int r = edges[e], c = edges[EE + e];
  if (t < 3) coord_diff[e * 3 + t] = x[r * 3 + t] - x[c * 3 + t];
  if (t < 64) { hin[t] = h[r * 64 + t]; hin[64 + t] = h[c * 64 + t]; }
  __syncthreads();
  float acc = eb1[t];
  for (int k = 0; k < 128; ++k) acc += hin[k] * ew1[k * 128 + t];
  hs[t] = silu_f(acc);
  __syncthreads();
  if (t < 64) {
    float o = eb2[t];
    for (int k = 0; k < 128; ++k) o += hs[k] * ew2[k * 64 + t];
    efn[e * 64 + t] = o;
  }
}

// ---------------- K2: constants c1 = MLP1(0), c2 = MLP2(0) -------------------
__global__ __launch_bounds__(128) void k_consts(
    const float* __restrict__ p1b1, const float* __restrict__ p1w2, const float* __restrict__ p1b2,
    const float* __restrict__ p2b1, const float* __restrict__ p2w2, const float* __restrict__ p2b2,
    float* __restrict__ c1, float* __restrict__ c2) {
  __shared__ float h1[128], h2[128];
  int t = threadIdx.x;
  h1[t] = silu_f(p1b1[t]); h2[t] = silu_f(p2b1[t]);
  __syncthreads();
  if (t < 64) {
    float a1 = p1b2[t], a2 = p2b2[t];
    for (int k = 0; k < 128; ++k) { a1 += h1[k] * p1w2[k * 64 + t]; a2 += h2[k] * p2w2[k * 64 + t]; }
    c1[t] = a1; c2[t] = a2;
  }
}

// ---------------- K2b: Wt[h][f] = bf16(p3w1[96+f][h]) (B-operand for MFMA) ---
__global__ __launch_bounds__(256) void k_prep(const float* __restrict__ p3w1,
                                              __hip_bfloat16* __restrict__ Wt) {
  int e = blockIdx.x * 256 + threadIdx.x;   // 8192 = 128 h x 64 f
  int hh = e >> 6, f = e & 63;
  Wt[hh * 64 + f] = __float2bfloat16(p3w1[(96 + f) * 128 + hh]);
}

// ---------------- K3: mark touched cells -------------------------------------
__global__ __launch_bounds__(256) void k_mark(const int* __restrict__ nb_edge,
                                              int* __restrict__ slotmap) {
  int m = blockIdx.x * 256 + threadIdx.x;
  if (m >= MM) return;
  int cell = nb_edge[m] * 512 + nb_edge[MM + m];
  atomicCAS(&slotmap[cell], -1, -2);
}

// ------ K4: compact marked cells -> slots (both orientations) ----------------
__global__ __launch_bounds__(256) void k_compact(int* __restrict__ slotmap,
                                                 int* __restrict__ slotmapT,
                                                 int* __restrict__ cells,
                                                 int* __restrict__ nC) {
  int cell = blockIdx.x * 256 + threadIdx.x;
  if (slotmap[cell] != -2) return;
  int s = atomicAdd(nC, 1);
  slotmap[cell] = s;
  slotmapT[(cell & 511) * 512 + (cell >> 9)] = s;
  cells[s] = cell;
}

// ---------------- K7: nb_feat scatter-add into COMPACT Tc (2 edges/block) ----
__global__ __launch_bounds__(192) void k_scatterT(
    const int* __restrict__ nb_edge, const int* __restrict__ slotmap,
    const float* __restrict__ coord_diff, const float* __restrict__ efn,
    float* __restrict__ Tc) {
  int t = threadIdx.x;
  int sub = (t >= 96) ? 1 : 0;
  int c = t - sub * 96;
  int m = blockIdx.x * 2 + sub;
  int a = nb_edge[m], b = nb_edge[MM + m];
  int s = slotmap[a * 512 + b];
  float val;
  if (c < 32) {
    float vtv = coord_diff[a * 3 + 0] * coord_diff[b * 3 + 0]
              + coord_diff[a * 3 + 1] * coord_diff[b * 3 + 1]
              + coord_diff[a * 3 + 2] * coord_diff[b * 3 + 2];
    int i = c >> 1;
    float ang = vtv * 16.0f * __expf(-0.57564627324851143f * (float)i);
    val = (c & 1) ? cosf(ang) : sinf(ang);
  } else {
    int f = c - 32;
    val = efn[a * 64 + f] * efn[b * 64 + f];
  }
  atomicAdd(&Tc[s * 96 + c], val);
}

// ------- K8: batched (8 cells/block) MLPs -> D1/D2, sums A,B; TWc = Tc@w1T ---
__global__ __launch_bounds__(128) void k_mlp96b(
    const int* __restrict__ cells, const int* __restrict__ nC, const float* __restrict__ Tc,
    const float* __restrict__ w11, const float* __restrict__ b11,
    const float* __restrict__ w12, const float* __restrict__ b12,
    const float* __restrict__ w21, const float* __restrict__ b21,
    const float* __restrict__ w22, const float* __restrict__ b22,
    const float* __restrict__ c1, const float* __restrict__ c2,
    const float* __restrict__ p3w1,
    float* __restrict__ D1, float* __restrict__ D2,
    float* __restrict__ A, float* __restrict__ B,
    float* __restrict__ TWc) {
  __shared__ float xsT[96 * 8];    // [k][cell] transposed for b128 reads
  __shared__ float hid[8][128];
  __shared__ int cl[8];
  int t = threadIdx.x;
  int nc = *nC;
  int s0 = blockIdx.x * 8;
  if (s0 >= nc) return;
  for (int e = t; e < 768; e += 128) xsT[(e % 96) * 8 + e / 96] = Tc[s0 * 96 + e];
  if (t < 8) cl[t] = (s0 + t < nc) ? cells[s0 + t] : 0;
  __syncthreads();
  float tw[8], a1[8], a2[8];
#pragma unroll
  for (int c = 0; c < 8; ++c) { tw[c] = 0.f; a1[c] = b11[t]; a2[c] = b21[t]; }
  for (int k = 0; k < 96; ++k) {
    float wt = p3w1[k * 128 + t];
    float w1v = w11[k * 128 + t];
    float w2v = w21[k * 128 + t];
    float4 xlo = *(const float4*)&xsT[k * 8];
    float4 xhi = *(const float4*)&xsT[k * 8 + 4];
    float xv[8] = {xlo.x, xlo.y, xlo.z, xlo.w, xhi.x, xhi.y, xhi.z, xhi.w};
#pragma unroll
    for (int c = 0; c < 8; ++c) {
      tw[c] += xv[c] * wt; a1[c] += xv[c] * w1v; a2[c] += xv[c] * w2v;
    }
  }
#pragma unroll
  for (int c = 0; c < 8; ++c) {
    if (s0 + c < nc) TWc[(s0 + c) * 128 + t] = tw[c];
    hid[c][t] = silu_f(a1[c]);
  }
  __syncthreads();
  {
    int hh = t & 63, cq = t >> 6;
    float o[4];
#pragma unroll
    for (int cc = 0; cc < 4; ++cc) o[cc] = b12[hh];
    for (int k = 0; k < 128; ++k) {
      float w = w12[k * 64 + hh];
#pragma unroll
      for (int cc = 0; cc < 4; ++cc) o[cc] += hid[cq * 4 + cc][k] * w;
    }
#pragma unroll
    for (int cc = 0; cc < 4; ++cc) {
      int c = cq * 4 + cc;
      if (s0 + c < nc) {
        float d = o[cc] - c1[hh];
        D1[(s0 + c) * 64 + hh] = d;
        atomicAdd(&A[(cl[c] >> 9) * 64 + hh], d);
      }
    }
  }
  __syncthreads();
#pragma unroll
  for (int c = 0; c < 8; ++c) hid[c][t] = silu_f(a2[c]);
  __syncthreads();
  {
    int hh = t & 63, cq = t >> 6;
    float o[4];
#pragma unroll
    for (int cc = 0; cc < 4; ++cc) o[cc] = b22[hh];
    for (int k = 0; k < 128; ++k) {
      float w = w22[k * 64 + hh];
#pragma unroll
      for (int cc = 0; cc < 4; ++cc) o[cc] += hid[cq * 4 + cc][k] * w;
    }
#pragma unroll
    for (int cc = 0; cc < 4; ++cc) {
      int c = cq * 4 + cc;
      if (s0 + c < nc) {
        float d = o[cc] - c2[hh];
        D2[(s0 + c) * 64 + hh] = d;
        atomicAdd(&B[(cl[c] & 511) * 64 + hh], d);
      }
    }
  }
}

// ---------------- K10: u[i] = b1 + (512 c1c2 + c2*A[i])@w1m ; v[j] = (c1*B[j])@w1m
__global__ __launch_bounds__(128) void k_uv(
    const float* __restrict__ A, const float* __restrict__ B,
    const float* __restrict__ c1, const float* __restrict__ c2,
    const float* __restrict__ p3w1, const float* __restrict__ p3b1,
    float* __restrict__ u, float* __restrict__ v) {
  __shared__ float vec[64];
  int i = blockIdx.x, y = blockIdx.y, t = threadIdx.x;
  if (t < 64)
    vec[t] = (y == 0) ? (512.0f * c1[t] * c2[t] + c2[t] * A[i * 64 + t])
                      : (c1[t] * B[i * 64 + t]);
  __syncthreads();
  float a = (y == 0) ? p3b1[t] : 0.f;
  for (int f = 0; f < 64; ++f) a += vec[f] * p3w1[(96 + f) * 128 + t];
  (y == 0 ? u : v)[i * 128 + t] = a;
}

// ---------------- K11a: densify compact D1/D2 into plane-major bf16 ----------
// y<64: D1d[f=y][i=bx][k=t] = D1[slotmap[i*512+k]][f] or 0   (coalesced write)
// y>=64: D2dT[f][j=bx][k=t] = D2[slotmapT[j*512+k]][f] or 0  (B^T planes)
__global__ __launch_bounds__(512) void k_densify(
    const int* __restrict__ slotmap, const int* __restrict__ slotmapT,
    const float* __restrict__ D1, const float* __restrict__ D2,
    __hip_bfloat16* __restrict__ D1d, __hip_bfloat16* __restrict__ D2dT) {
  int k = threadIdx.x;
  int i = blockIdx.x;
  int y = blockIdx.y;
  if (y < 64) {
    int f = y;
    int s = slotmap[i * 512 + k];
    float v = (s >= 0) ? D1[s * 64 + f] : 0.f;
    D1d[(f * 512 + i) * 512 + k] = __float2bfloat16(v);
  } else {
    int f = y - 64;
    int s = slotmapT[i * 512 + k];
    float v = (s >= 0) ? D2[s * 64 + f] : 0.f;
    D2dT[(f * 512 + i) * 512 + k] = __float2bfloat16(v);
  }
}

// ---------------- K11b: batched plane GEMM S_f = A_f * B_f (MFMA) ------------
// 1024 blocks = 64 f x (4x4) 128x128 tiles; 256 thr = 4 waves (2x2), wave 64x64.
// A = D1d[f] rows [i][k]; B^T = D2dT[f] rows [j][k] -> both staged as row-major
// LDS tiles (stride 40 shorts = 80 B, 2-way banks). BK=32, 16 K-iters.
__global__ __launch_bounds__(256) void k_einsum_mfma(
    const __hip_bfloat16* __restrict__ D1d,
    const __hip_bfloat16* __restrict__ D2dT,
    __hip_bfloat16* __restrict__ S_fij) {
  __shared__ short As[128 * 40];
  __shared__ short Bs[128 * 40];
  int b = blockIdx.x;
  int f = b >> 4;
  int i0 = ((b >> 2) & 3) * 128, j0 = (b & 3) * 128;
  int t = threadIdx.x;
  int w = t >> 6, lane = t & 63;
  int wy = w >> 1, wx = w & 1;
  int q = lane >> 4, l15 = lane & 15;
  const short* Ap = (const short*)D1d + f * 262144;
  const short* Bp = (const short*)D2dT + f * 262144;
  int row = t >> 1, seg = t & 1;   // staging: 128 rows x 2 segments of 16
  v4f acc[4][4];
#pragma unroll
  for (int yi = 0; yi < 4; ++yi)
#pragma unroll
    for (int xj = 0; xj < 4; ++xj) acc[yi][xj] = (v4f){0.f, 0.f, 0.f, 0.f};
  for (int k0 = 0; k0 < 512; k0 += 32) {
    __syncthreads();
    const short8v* ga = (const short8v*)&Ap[(i0 + row) * 512 + k0 + seg * 16];
    const short8v* gb = (const short8v*)&Bp[(j0 + row) * 512 + k0 + seg * 16];
    *(short8v*)&As[row * 40 + seg * 16] = ga[0];
    *(short8v*)&As[row * 40 + seg * 16 + 8] = ga[1];
    *(short8v*)&Bs[row * 40 + seg * 16] = gb[0];
    *(short8v*)&Bs[row * 40 + seg * 16 + 8] = gb[1];
    __syncthreads();
    short8v af[4], bf[4];
#pragma unroll
    for (int x = 0; x < 4; ++x) {
      af[x] = *(const short8v*)&As[(wy * 64 + x * 16 + l15) * 40 + q * 8];
      bf[x] = *(const short8v*)&Bs[(wx * 64 + x * 16 + l15) * 40 + q * 8];
    }
#pragma unroll
    for (int yi = 0; yi < 4; ++yi)
#pragma unroll
      for (int xj = 0; xj < 4; ++xj)
        acc[yi][xj] = __builtin_amdgcn_mfma_f32_16x16x32_bf16(af[yi], bf[xj], acc[yi][xj], 0, 0, 0);
  }
  // C layout: col j = l15, row i = q*4 + r  [m89-verified]
#pragma unroll
  for (int yi = 0; yi < 4; ++yi)
#pragma unroll
    for (int r = 0; r < 4; ++r) {
      int irow = i0 + wy * 64 + yi * 16 + q * 4 + r;
#pragma unroll
      for (int xj = 0; xj < 4; ++xj)
        S_fij[(f * 512 + irow) * 512 + j0 + wx * 64 + xj * 16 + l15] =
            __float2bfloat16(acc[yi][xj][r]);
    }
}

// ------- K12: MFMA z = S@Wt + u[i]+v[j]+TW, silu, row/col/diag reduce --------
// Block = 8x8 cells (bi,bj); 4 waves; wave w owns cells w*16..w*16+15.
// S consumed from plane-major S_fij via an LDS transpose stage (pad 72).
// C layout: h = n0+(lane&15), cell = w*16 + quad*4 + reg  [m89-verified].
__global__ __launch_bounds__(256) void k_tout_mfma(
    const __hip_bfloat16* __restrict__ S_fij, const float* __restrict__ u,
    const float* __restrict__ v, const float* __restrict__ TWc,
    const int* __restrict__ slotmap, const __hip_bfloat16* __restrict__ Wt,
    float* __restrict__ row_part, float* __restrict__ col_part,
    float* __restrict__ diag_silu) {
  __shared__ __hip_bfloat16 WtL[128 * 72];   // 18,432 B
  __shared__ short Ss[64 * 72];              // [cell][f] pad 72 -> 9,216 B
  __shared__ float uvL[2048];                // 8 KB
  __shared__ float colbuf[4][8][128];        // 16 KB
  __shared__ int slotL[64];
  int t = threadIdx.x;
  int w = t >> 6, lane = t & 63;
  int q = lane >> 4, l15 = lane & 15;
  int bi = blockIdx.x >> 6, bj = blockIdx.x & 63;
  int i0 = bi * 8, j0 = bj * 8;
  for (int e = t; e < 4096; e += 256) {
    int row = e >> 5, c2 = e & 31;
    ((unsigned*)WtL)[row * 36 + c2] = ((const unsigned*)Wt)[row * 32 + c2];
  }
  // stage S-tile: 512 chunks (f, ii): 8 j-cells each, transpose into [cell][f]
  for (int c = t; c < 512; c += 256) {
    int f = c >> 3, ii = c & 7;
    short8v vch = *(const short8v*)((const short*)S_fij + (f * 512 + i0 + ii) * 512 + j0);
#pragma unroll
    for (int jj = 0; jj < 8; ++jj) Ss[(ii * 8 + jj) * 72 + f] = vch[jj];
  }
  for (int e = t; e < 1024; e += 256) uvL[e] = u[(i0 + (e >> 7)) * 128 + (e & 127)];
  for (int e = t; e < 1024; e += 256) uvL[1024 + e] = v[(j0 + (e >> 7)) * 128 + (e & 127)];
  if (t < 64) slotL[t] = slotmap[(i0 + (t >> 3)) * 512 + j0 + (t & 7)];
  __syncthreads();
  int cellA = w * 16 + l15;
  short8v a0 = *(const short8v*)&Ss[cellA * 72 + q * 8];
  short8v a1 = *(const short8v*)&Ss[cellA * 72 + 32 + q * 8];
  v4f acc[8];
#pragma unroll
  for (int nt = 0; nt < 8; ++nt) {
    const short8v* b0 = (const short8v*)&WtL[(nt * 16 + l15) * 72 + q * 8];
    const short8v* b1 = (const short8v*)&WtL[(nt * 16 + l15) * 72 + 32 + q * 8];
    v4f c = {0.f, 0.f, 0.f, 0.f};
    c = __builtin_amdgcn_mfma_f32_16x16x32_bf16(a0, *b0, c, 0, 0, 0);
    c = __builtin_amdgcn_mfma_f32_16x16x32_bf16(a1, *b1, c, 0, 0, 0);
    acc[nt] = c;
  }
  float colp[8][4];
#pragma unroll
  for (int nt = 0; nt < 8; ++nt) {
    int hh = nt * 16 + l15;
    float rsum = 0.f;
#pragma unroll
    for (int r = 0; r < 4; ++r) {
      int c = w * 16 + q * 4 + r;
      int iL = c >> 3, jL = c & 7;
      float z = acc[nt][r] + uvL[iL * 128 + hh] + uvL[1024 + jL * 128 + hh];
      int s = slotL[c];
      if (s >= 0) z += TWc[s * 128 + hh];
      float sv = silu_f(z);
      rsum += sv;
      colp[nt][r] = sv + __shfl_xor(sv, 32);
      if (bi == bj && iL == jL) diag_silu[(i0 + iL) * 128 + hh] = sv;
    }
    rsum += __shfl_xor(rsum, 16);
    if ((q & 1) == 0)
      row_part[(bj * 512 + i0 + 2 * w + (q >> 1)) * 128 + hh] = rsum;
  }
  if (q < 2) {
#pragma unroll
    for (int nt = 0; nt < 8; ++nt)
#pragma unroll
      for (int r = 0; r < 4; ++r)
        colbuf[w][q * 4 + r][nt * 16 + l15] = colp[nt][r];
  }
  __syncthreads();
  for (int e = t; e < 1024; e += 256) {
    int jL = e >> 7, hh = e & 127;
    float a = colbuf[0][jL][hh] + colbuf[1][jL][hh] + colbuf[2][jL][hh] + colbuf[3][jL][hh];
    col_part[(bi * 512 + j0 + jL) * 128 + hh] = a;
  }
}

// ---------------- K13: reduce 64 partial slices ------------------------------
__global__ __launch_bounds__(256) void k_sumparts(
    const float* __restrict__ row_part, const float* __restrict__ col_part,
    float* __restrict__ rowsum, float* __restrict__ colsum) {
  int i = blockIdx.x, t = threadIdx.x;
  const float* src = (t < 128) ? row_part : col_part;
  float* dst = (t < 128) ? rowsum : colsum;
  int hc = t & 127;
  float a = 0.f;
  for (int p = 0; p < 64; ++p) a += src[(p * 512 + i) * 128 + hc];
  dst[i * 128 + hc] = a;
}

// ---------------- K14: second layer of p3 MLP on reduced silu sums -----------
__global__ __launch_bounds__(64) void k_tout2(
    const float* __restrict__ diag_silu, const float* __restrict__ rowsum_silu,
    const float* __restrict__ colsum_silu,
    const float* __restrict__ w2, const float* __restrict__ b2,
    float* __restrict__ diag_T, float* __restrict__ row_T, float* __restrict__ col_T) {
  __shared__ float in[128];
  int e = blockIdx.x, which = blockIdx.y, t = threadIdx.x;
  const float* src = (which == 0) ? diag_silu : (which == 1) ? rowsum_silu : colsum_silu;
  in[t] = src[e * 128 + t]; in[64 + t] = src[e * 128 + 64 + t];
  __syncthreads();
  float a = 0.f;
  for (int k = 0; k < 128; ++k) a += in[k] * w2[k * 64 + t];
  float bias = b2[t] * ((which == 0) ? 1.0f : 512.0f);
  float* dst = (which == 0) ? diag_T : (which == 1) ? row_T : col_T;
  dst[e * 64 + t] = a + bias;
}

// ---------------- K15: tot / tr ----------------------------------------------
__global__ __launch_bounds__(128) void k_totr(
    const float* __restrict__ row_T, const float* __restrict__ diag_T,
    float* __restrict__ tot, float* __restrict__ tr) {
  int t = threadIdx.x;
  const float* src = (t < 64) ? row_T : diag_T;
  int f = t & 63;
  float a = 0.f;
  for (int e = 0; e < 512; ++e) a += src[e * 64 + f];
  if (t < 64) tot[f] = a; else tr[f] = a;
}

// ---------------- K16: nb_t1 = [diag|row|col|tot|tr] @ ign_w + ign_b ---------
__global__ __launch_bounds__(64) void k_nbt1(
    const float* __restrict__ diag_T, const float* __restrict__ row_T,
    const float* __restrict__ col_T, const float* __restrict__ tot,
    const float* __restrict__ tr,
    const float* __restrict__ gw, const float* __restrict__ gb,
    float* __restrict__ nb_t1) {
  __shared__ float in[320];
  int e = blockIdx.x, t = threadIdx.x;
  in[t] = diag_T[e * 64 + t]; in[64 + t] = row_T[e * 64 + t];
  in[128 + t] = col_T[e * 64 + t]; in[192 + t] = tot[t]; in[256 + t] = tr[t];
  __syncthreads();
  float a = gb[t];
  for (int k = 0; k < 320; ++k) a += in[k] * gw[k * 64 + t];
  nb_t1[e * 64 + t] = a;
}

// ----- K17: coord weight w_e, seg/cnt/nb_t0 scatters, edge_attr passthrough --
__global__ __launch_bounds__(128) void k_edge_out(
    const int* __restrict__ edges, const float* __restrict__ coord_diff,
    const float* __restrict__ nb_t1, const float* __restrict__ edge_attr,
    const float* __restrict__ cw1, const float* __restrict__ cb1,
    const float* __restrict__ cw2,
    float* __restrict__ seg, float* __restrict__ cnt, float* __restrict__ nb_t0,
    float* __restrict__ out_ea) {
  __shared__ float in[64];
  __shared__ float red[128];
  int e = blockIdx.x, t = threadIdx.x;
  if (t < 64) in[t] = nb_t1[e * 64 + t];
  __syncthreads();
  float a = cb1[t];
  for (int k = 0; k < 64; ++k) a += in[k] * cw1[k * 128 + t];
  red[t] = silu_f(a) * cw2[t];
  __syncthreads();
  for (int s2 = 64; s2 > 0; s2 >>= 1) {
    if (t < s2) red[t] += red[t + s2];
    __syncthreads();
  }
  float w = red[0];
  int r = edges[e];
  if (t < 3) atomicAdd(&seg[r * 3 + t], coord_diff[e * 3 + t] * w);
  if (t == 64) atomicAdd(&cnt[r], 1.0f);
  if (t < 64) atomicAdd(&nb_t0[r * 64 + t], in[t]);
  if (t < 4) out_ea[e * 4 + t] = edge_attr[e * 4 + t];
}

// ---------------- K18: x_new and h_new ---------------------------------------
__global__ __launch_bounds__(128) void k_node_out(
    const float* __restrict__ h, const float* __restrict__ x,
    const float* __restrict__ seg, const float* __restrict__ cnt,
    const float* __restrict__ nb_t0,
    const float* __restrict__ w1, const float* __restrict__ b1,
    const float* __restrict__ w2, const float* __restrict__ b2,
    float* __restrict__ out_h, float* __restrict__ out_x) {
  __shared__ float in[64];
  __shared__ float hs[128];
  int n = blockIdx.x, t = threadIdx.x;
  if (t < 3) {
    float c = cnt[n]; if (c < 1.f) c = 1.f;
    out_x[n * 3 + t] = x[n * 3 + t] + seg[n * 3 + t] / c;
  }
  if (t < 64) in[t] = nb_t0[n * 64 + t];
  __syncthreads();
  float a = b1[t];
  for (int k = 0; k < 64; ++k) a += in[k] * w1[k * 128 + t];
  hs[t] = silu_f(a);
  __syncthreads();
  if (t < 64) {
    float o = b2[t];
    for (int k = 0; k < 128; ++k) o += hs[k] * w2[k * 64 + t];
    out_h[n * 64 + t] = h[n * 64 + t] + o;
  }
}

extern "C" void kernel_launch(void* const* d_in, const int* in_sizes, int n_in,
                              void* d_out, int out_size, void* d_ws, size_t ws_size,
                              hipStream_t stream) {
  (void)in_sizes; (void)n_in; (void)out_size; (void)ws_size;
  const float* h  = (const float*)d_in[0];
  const float* x  = (const float*)d_in[1];
  const int* edges   = (const int*)d_in[2];
  const int* nb_edge = (const int*)d_in[3];
  const float* edge_attr = (const float*)d_in[4];
  const float* ew1 = (const float*)d_in[6],  *eb1 = (const float*)d_in[7];
  const float* ew2 = (const float*)d_in[8],  *eb2 = (const float*)d_in[9];
  const float* p1w1 = (const float*)d_in[10], *p1b1 = (const float*)d_in[11];
  const float* p1w2 = (const float*)d_in[12], *p1b2 = (const float*)d_in[13];
  const float* p2w1 = (const float*)d_in[14], *p2b1 = (const float*)d_in[15];
  const float* p2w2 = (const float*)d_in[16], *p2b2 = (const float*)d_in[17];
  const float* p3w1 = (const float*)d_in[18], *p3b1 = (const float*)d_in[19];
  const float* p3w2 = (const float*)d_in[20], *p3b2 = (const float*)d_in[21];
  const float* ignw = (const float*)d_in[22], *ignb = (const float*)d_in[23];
  const float* cw1 = (const float*)d_in[24], *cb1 = (const float*)d_in[25];
  const float* cw2 = (const float*)d_in[26];
  const float* ndw1 = (const float*)d_in[27], *ndb1 = (const float*)d_in[28];
  const float* ndw2 = (const float*)d_in[29], *ndb2 = (const float*)d_in[30];

  // ---- workspace layout (~162 MB) ----
  char* ws = (char*)d_ws;
  __hip_bfloat16* D1d  = (__hip_bfloat16*)(ws + 0);          // [64][512][512] = 33,554,432 B
  __hip_bfloat16* D2dT = (__hip_bfloat16*)(ws + 33554432);   // 33,554,432 B
  __hip_bfloat16* S_fij = (__hip_bfloat16*)(ws + 67108864);  // 33,554,432 B
  float* row_part = (float*)(ws + 100663296);                // [64][512][128] = 16,777,216 B
  float* col_part = (float*)(ws + 117440512);                // 16,777,216 B
  // ---- single zero-memset block [134,217,728 .. 140,910,608) ----
  float* Tc    = (float*)(ws + 134217728);                   // [16384][96] = 6,291,456 B
  int*   nC    = (int*)(ws + 140509184);                     // 1 int (+pad to 16)
  float* A     = (float*)(ws + 140509200);                   // 32768 floats
  float* B     = (float*)(ws + 140640272);                   // 32768 floats
  float* seg   = (float*)(ws + 140771344);                   // 1536 floats
  float* cnt   = (float*)(ws + 140777488);                   // 512 floats
  float* nb_t0 = (float*)(ws + 140779536);                   // 32768 floats -> end 140,910,608
  // ---- rest ----
  int*   slotmap  = (int*)(ws + 140910608);                  // 262144 ints (0xFF)
  int*   slotmapT = (int*)(ws + 141959184);                  // 262144 ints (0xFF)
  int*   cells    = (int*)(ws + 143007760);                  // 16384 ints
  float* D1       = (float*)(ws + 143073296);                // [16384][64]
  float* D2       = (float*)(ws + 147267600);                // [16384][64]
  float* TWc      = (float*)(ws + 151461904);                // [16384][128]
  float* c1       = (float*)(ws + 159850512);                // 64
  float* c2       = (float*)(ws + 159850768);                // 64
  float* u        = (float*)(ws + 159851024);                // [512][128]
  float* v        = (float*)(ws + 160113168);                // [512][128]
  float* coord_diff  = (float*)(ws + 160375312);             // [512][3]
  float* efn         = (float*)(ws + 160381456);             // [512][64]
  float* diag_silu   = (float*)(ws + 160512528);             // [512][128]
  float* rowsum_silu = (float*)(ws + 160774672);
  float* colsum_silu = (float*)(ws + 161036816);
  float* diag_T      = (float*)(ws + 161298960);             // [512][64]
  float* row_T       = (float*)(ws + 161430032);
  float* col_T       = (float*)(ws + 161561104);
  float* tot         = (float*)(ws + 161692176);             // 64
  float* tr          = (float*)(ws + 161692432);             // 64
  float* nb_t1       = (float*)(ws + 161692688);             // [512][64]
  __hip_bfloat16* Wt = (__hip_bfloat16*)(ws + 161823760);    // [128][64] -> end 161,840,144

  float* out_h  = (float*)d_out;
  float* out_x  = out_h + 512 * 64;
  float* out_ea = out_x + 512 * 3;

  hipMemsetAsync(slotmap, 0xFF, 2097152, stream);            // slotmap + slotmapT = -1
  hipMemsetAsync(ws + 134217728, 0, 6692880, stream);        // Tc..nb_t0

  k_edge<<<512, 128, 0, stream>>>(h, x, edges, ew1, eb1, ew2, eb2, coord_diff, efn);
  k_consts<<<1, 128, 0, stream>>>(p1b1, p1w2, p1b2, p2b1, p2w2, p2b2, c1, c2);
  k_prep<<<32, 256, 0, stream>>>(p3w1, Wt);
  k_mark<<<64, 256, 0, stream>>>(nb_edge, slotmap);
  k_compact<<<1024, 256, 0, stream>>>(slotmap, slotmapT, cells, nC);
  k_scatterT<<<8192, 192, 0, stream>>>(nb_edge, slotmap, coord_diff, efn, Tc);
  k_mlp96b<<<2048, 128, 0, stream>>>(cells, nC, Tc,
                                     p1w1, p1b1, p1w2, p1b2,
                                     p2w1, p2b1, p2w2, p2b2,
                                     c1, c2, p3w1, D1, D2, A, B, TWc);
  k_uv<<<dim3(512, 2), 128, 0, stream>>>(A, B, c1, c2, p3w1, p3b1, u, v);
  k_densify<<<dim3(512, 128), 512, 0, stream>>>(slotmap, slotmapT, D1, D2, D1d, D2dT);
  k_einsum_mfma<<<1024, 256, 0, stream>>>(D1d, D2dT, S_fij);
  k_tout_mfma<<<4096, 256, 0, stream>>>(S_fij, u, v, TWc, slotmap, Wt,
                                        row_part, col_part, diag_silu);
  k_sumparts<<<512, 256, 0, stream>>>(row_part, col_part, rowsum_silu, colsum_silu);
  k_tout2<<<dim3(512, 3), 64, 0, stream>>>(diag_silu, rowsum_silu, colsum_silu,
                                           p3w2, p3b2, diag_T, row_T, col_T);
  k_totr<<<1, 128, 0, stream>>>(row_T, diag_T, tot, tr);
  k_nbt1<<<512, 64, 0, stream>>>(diag_T, row_T, col_T, tot, tr, ignw, ignb, nb_t1);
  k_edge_out<<<512, 128, 0, stream>>>(edges, coord_diff, nb_t1, edge_attr,
                                      cw1, cb1, cw2, seg, cnt, nb_t0, out_ea);
  k_node_out<<<512, 128, 0, stream>>>(h, x, seg, cnt, nb_t0,
                                      ndw1, ndb1, ndw2, ndb2, out_h, out_x);
}

// Round 11
// 454.602 us; speedup vs baseline: 1.1110x; 1.0035x over previous
//
#include <hip/hip_runtime.h>
#include <hip/hip_bf16.h>

// Problem constants (static per reference)
#define NN   512    // nodes
#define EE   512    // edges == nb-graph nodes (En)
#define MM   16384  // nb-graph edges

typedef float v4f __attribute__((ext_vector_type(4)));
typedef short short8v __attribute__((ext_vector_type(8)));

__device__ __forceinline__ float silu_f(float v) { return v / (1.0f + __expf(-v)); }

// ---------------- K1: per original edge: coord_diff + efn = MLP([h_r|h_c]) ----
__global__ __launch_bounds__(128) void k_edge(
    const float* __restrict__ h, const float* __restrict__ x,
    const int* __restrict__ edges,
    const float* __restrict__ ew1, const float* __restrict__ eb1,
    const float* __restrict__ ew2, const float* __restrict__ eb2,
    float* __restrict__ coord_diff, float* __restrict__ efn) {
  __shared__ float hin[128];
  __shared__ float hs[128];
  int e = blockIdx.x;
  int t = threadIdx.x;
  int r = edges[e], c = edges[EE + e];
  if (t < 3) coord_diff[e * 3 + t] = x[r * 3 + t] - x[c * 3 + t];
  if (t < 64) { hin[t] = h[r * 64 + t]; hin[64 + t] = h[c * 64 + t]; }
  __syncthreads();
  float acc = eb1[t];
  for (int k = 0; k < 128; ++k) acc += hin[k] * ew1[k * 128 + t];
  hs[t] = silu_f(acc);
  __syncthreads();
  if (t < 64) {
    float o = eb2[t];
    for (int k = 0; k < 128; ++k) o += hs[k] * ew2[k * 64 + t];
    efn[e * 64 + t] = o;
  }
}

// ---------------- K2: constants c1 = MLP1(0), c2 = MLP2(0) -------------------
__global__ __launch_bounds__(128) void k_consts(
    const float* __restrict__ p1b1, const float* __restrict__ p1w2, const float* __restrict__ p1b2,
    const float* __restrict__ p2b1, const float* __restrict__ p2w2, const float* __restrict__ p2b2,
    float* __restrict__ c1, float* __restrict__ c2) {
  __shared__ float h1[128], h2[128];
  int t = threadIdx.x;
  h1[t] = silu_f(p1b1[t]); h2[t] = silu_f(p2b1[t]);
  __syncthreads();
  if (t < 64) {
    float a1 = p1b2[t], a2 = p2b2[t];
    for (int k = 0; k < 128; ++k) { a1 += h1[k] * p1w2[k * 64 + t]; a2 += h2[k] * p2w2[k * 64 + t]; }
    c1[t] = a1; c2[t] = a2;
  }
}

// ---------------- K2b: Wt[h][f] = bf16(p3w1[96+f][h]) (B-operand for MFMA) ---
__global__ __launch_bounds__(256) void k_prep(const float* __restrict__ p3w1,
                                              __hip_bfloat16* __restrict__ Wt) {
  int e = blockIdx.x * 256 + threadIdx.x;   // 8192 = 128 h x 64 f
  int hh = e >> 6, f = e & 63;
  Wt[hh * 64 + f] = __float2bfloat16(p3w1[(96 + f) * 128 + hh]);
}

// ---------------- K3: mark touched cells -------------------------------------
__global__ __launch_bounds__(256) void k_mark(const int* __restrict__ nb_edge,
                                              int* __restrict__ slotmap) {
  int m = blockIdx.x * 256 + threadIdx.x;
  if (m >= MM) return;
  int cell = nb_edge[m] * 512 + nb_edge[MM + m];
  atomicCAS(&slotmap[cell], -1, -2);
}

// ------ K4: compact marked cells -> slots (both orientations) ----------------
__global__ __launch_bounds__(256) void k_compact(int* __restrict__ slotmap,
                                                 int* __restrict__ slotmapT,
                                                 int* __restrict__ cells,
                                                 int* __restrict__ nC) {
  int cell = blockIdx.x * 256 + threadIdx.x;
  if (slotmap[cell] != -2) return;
  int s = atomicAdd(nC, 1);
  slotmap[cell] = s;
  slotmapT[(cell & 511) * 512 + (cell >> 9)] = s;
  cells[s] = cell;
}

// ---------------- K7: nb_feat scatter-add into COMPACT Tc (2 edges/block) ----
__global__ __launch_bounds__(192) void k_scatterT(
    const int* __restrict__ nb_edge, const int* __restrict__ slotmap,
    const float* __restrict__ coord_diff, const float* __restrict__ efn,
    float* __restrict__ Tc) {
  int t = threadIdx.x;
  int sub = (t >= 96) ? 1 : 0;
  int c = t - sub * 96;
  int m = blockIdx.x * 2 + sub;
  int a = nb_edge[m], b = nb_edge[MM + m];
  int s = slotmap[a * 512 + b];
  float val;
  if (c < 32) {
    float vtv = coord_diff[a * 3 + 0] * coord_diff[b * 3 + 0]
              + coord_diff[a * 3 + 1] * coord_diff[b * 3 + 1]
              + coord_diff[a * 3 + 2] * coord_diff[b * 3 + 2];
    int i = c >> 1;
    float ang = vtv * 16.0f * __expf(-0.57564627324851143f * (float)i);
    val = (c & 1) ? cosf(ang) : sinf(ang);
  } else {
    int f = c - 32;
    val = efn[a * 64 + f] * efn[b * 64 + f];
  }
  atomicAdd(&Tc[s * 96 + c], val);
}

// ------- K8: batched (8 cells/block) MLPs -> D1/D2, sums A,B; TWc = Tc@w1T ---
__global__ __launch_bounds__(128) void k_mlp96b(
    const int* __restrict__ cells, const int* __restrict__ nC, const float* __restrict__ Tc,
    const float* __restrict__ w11, const float* __restrict__ b11,
    const float* __restrict__ w12, const float* __restrict__ b12,
    const float* __restrict__ w21, const float* __restrict__ b21,
    const float* __restrict__ w22, const float* __restrict__ b22,
    const float* __restrict__ c1, const float* __restrict__ c2,
    const float* __restrict__ p3w1,
    float* __restrict__ D1, float* __restrict__ D2,
    float* __restrict__ A, float* __restrict__ B,
    float* __restrict__ TWc) {
  __shared__ float xsT[96 * 8];    // [k][cell] transposed for b128 reads
  __shared__ float hid[8][128];
  __shared__ int cl[8];
  int t = threadIdx.x;
  int nc = *nC;
  int s0 = blockIdx.x * 8;
  if (s0 >= nc) return;
  for (int e = t; e < 768; e += 128) xsT[(e % 96) * 8 + e / 96] = Tc[s0 * 96 + e];
  if (t < 8) cl[t] = (s0 + t < nc) ? cells[s0 + t] : 0;
  __syncthreads();
  float tw[8], a1[8], a2[8];
#pragma unroll
  for (int c = 0; c < 8; ++c) { tw[c] = 0.f; a1[c] = b11[t]; a2[c] = b21[t]; }
  for (int k = 0; k < 96; ++k) {
    float wt = p3w1[k * 128 + t];
    float w1v = w11[k * 128 + t];
    float w2v = w21[k * 128 + t];
    float4 xlo = *(const float4*)&xsT[k * 8];
    float4 xhi = *(const float4*)&xsT[k * 8 + 4];
    float xv[8] = {xlo.x, xlo.y, xlo.z, xlo.w, xhi.x, xhi.y, xhi.z, xhi.w};
#pragma unroll
    for (int c = 0; c < 8; ++c) {
      tw[c] += xv[c] * wt; a1[c] += xv[c] * w1v; a2[c] += xv[c] * w2v;
    }
  }
#pragma unroll
  for (int c = 0; c < 8; ++c) {
    if (s0 + c < nc) TWc[(s0 + c) * 128 + t] = tw[c];
    hid[c][t] = silu_f(a1[c]);
  }
  __syncthreads();
  {
    int hh = t & 63, cq = t >> 6;
    float o[4];
#pragma unroll
    for (int cc = 0; cc < 4; ++cc) o[cc] = b12[hh];
    for (int k = 0; k < 128; ++k) {
      float w = w12[k * 64 + hh];
#pragma unroll
      for (int cc = 0; cc < 4; ++cc) o[cc] += hid[cq * 4 + cc][k] * w;
    }
#pragma unroll
    for (int cc = 0; cc < 4; ++cc) {
      int c = cq * 4 + cc;
      if (s0 + c < nc) {
        float d = o[cc] - c1[hh];
        D1[(s0 + c) * 64 + hh] = d;
        atomicAdd(&A[(cl[c] >> 9) * 64 + hh], d);
      }
    }
  }
  __syncthreads();
#pragma unroll
  for (int c = 0; c < 8; ++c) hid[c][t] = silu_f(a2[c]);
  __syncthreads();
  {
    int hh = t & 63, cq = t >> 6;
    float o[4];
#pragma unroll
    for (int cc = 0; cc < 4; ++cc) o[cc] = b22[hh];
    for (int k = 0; k < 128; ++k) {
      float w = w22[k * 64 + hh];
#pragma unroll
      for (int cc = 0; cc < 4; ++cc) o[cc] += hid[cq * 4 + cc][k] * w;
    }
#pragma unroll
    for (int cc = 0; cc < 4; ++cc) {
      int c = cq * 4 + cc;
      if (s0 + c < nc) {
        float d = o[cc] - c2[hh];
        D2[(s0 + c) * 64 + hh] = d;
        atomicAdd(&B[(cl[c] & 511) * 64 + hh], d);
      }
    }
  }
}

// ---------------- K10: u[i] = b1 + (512 c1c2 + c2*A[i])@w1m ; v[j] = (c1*B[j])@w1m
__global__ __launch_bounds__(128) void k_uv(
    const float* __restrict__ A, const float* __restrict__ B,
    const float* __restrict__ c1, const float* __restrict__ c2,
    const float* __restrict__ p3w1, const float* __restrict__ p3b1,
    float* __restrict__ u, float* __restrict__ v) {
  __shared__ float vec[64];
  int i = blockIdx.x, y = blockIdx.y, t = threadIdx.x;
  if (t < 64)
    vec[t] = (y == 0) ? (512.0f * c1[t] * c2[t] + c2[t] * A[i * 64 + t])
                      : (c1[t] * B[i * 64 + t]);
  __syncthreads();
  float a = (y == 0) ? p3b1[t] : 0.f;
  for (int f = 0; f < 64; ++f) a += vec[f] * p3w1[(96 + f) * 128 + t];
  (y == 0 ? u : v)[i * 128 + t] = a;
}

// ---------------- K11a: densify compact D1/D2 into plane-major bf16 ----------
__global__ __launch_bounds__(512) void k_densify(
    const int* __restrict__ slotmap, const int* __restrict__ slotmapT,
    const float* __restrict__ D1, const float* __restrict__ D2,
    __hip_bfloat16* __restrict__ D1d, __hip_bfloat16* __restrict__ D2dT) {
  int k = threadIdx.x;
  int i = blockIdx.x;
  int y = blockIdx.y;
  if (y < 64) {
    int f = y;
    int s = slotmap[i * 512 + k];
    float v = (s >= 0) ? D1[s * 64 + f] : 0.f;
    D1d[(f * 512 + i) * 512 + k] = __float2bfloat16(v);
  } else {
    int f = y - 64;
    int s = slotmapT[i * 512 + k];
    float v = (s >= 0) ? D2[s * 64 + f] : 0.f;
    D2dT[(f * 512 + i) * 512 + k] = __float2bfloat16(v);
  }
}

// ---------------- K11b: batched plane GEMM S_f = A_f * B_f (MFMA) ------------
__global__ __launch_bounds__(256) void k_einsum_mfma(
    const __hip_bfloat16* __restrict__ D1d,
    const __hip_bfloat16* __restrict__ D2dT,
    __hip_bfloat16* __restrict__ S_fij) {
  __shared__ short As[128 * 40];
  __shared__ short Bs[128 * 40];
  int b = blockIdx.x;
  int f = b >> 4;
  int i0 = ((b >> 2) & 3) * 128, j0 = (b & 3) * 128;
  int t = threadIdx.x;
  int w = t >> 6, lane = t & 63;
  int wy = w >> 1, wx = w & 1;
  int q = lane >> 4, l15 = lane & 15;
  const short* Ap = (const short*)D1d + f * 262144;
  const short* Bp = (const short*)D2dT + f * 262144;
  int row = t >> 1, seg = t & 1;   // staging: 128 rows x 2 segments of 16
  v4f acc[4][4];
#pragma unroll
  for (int yi = 0; yi < 4; ++yi)
#pragma unroll
    for (int xj = 0; xj < 4; ++xj) acc[yi][xj] = (v4f){0.f, 0.f, 0.f, 0.f};
  for (int k0 = 0; k0 < 512; k0 += 32) {
    __syncthreads();
    const short8v* ga = (const short8v*)&Ap[(i0 + row) * 512 + k0 + seg * 16];
    const short8v* gb = (const short8v*)&Bp[(j0 + row) * 512 + k0 + seg * 16];
    *(short8v*)&As[row * 40 + seg * 16] = ga[0];
    *(short8v*)&As[row * 40 + seg * 16 + 8] = ga[1];
    *(short8v*)&Bs[row * 40 + seg * 16] = gb[0];
    *(short8v*)&Bs[row * 40 + seg * 16 + 8] = gb[1];
    __syncthreads();
    short8v af[4], bf[4];
#pragma unroll
    for (int x = 0; x < 4; ++x) {
      af[x] = *(const short8v*)&As[(wy * 64 + x * 16 + l15) * 40 + q * 8];
      bf[x] = *(const short8v*)&Bs[(wx * 64 + x * 16 + l15) * 40 + q * 8];
    }
#pragma unroll
    for (int yi = 0; yi < 4; ++yi)
#pragma unroll
      for (int xj = 0; xj < 4; ++xj)
        acc[yi][xj] = __builtin_amdgcn_mfma_f32_16x16x32_bf16(af[yi], bf[xj], acc[yi][xj], 0, 0, 0);
  }
  // C layout: col j = l15, row i = q*4 + r  [m89-verified]
#pragma unroll
  for (int yi = 0; yi < 4; ++yi)
#pragma unroll
    for (int r = 0; r < 4; ++r) {
      int irow = i0 + wy * 64 + yi * 16 + q * 4 + r;
#pragma unroll
      for (int xj = 0; xj < 4; ++xj)
        S_fij[(f * 512 + irow) * 512 + j0 + wx * 64 + xj * 16 + l15] =
            __float2bfloat16(acc[yi][xj][r]);
    }
}

// ---------------- K11c: transpose S_fij [64][262144] -> S [262144][64] -------
// 64 ij x 64 f tile per block via XOR-swizzled LDS (row stride 72 shorts):
// global reads/writes are full 128 B runs; LDS writes <=2 lanes/bank (free);
// LDS reads aligned b128.
__global__ __launch_bounds__(256) void k_transpose(
    const __hip_bfloat16* __restrict__ S_fij, __hip_bfloat16* __restrict__ S) {
  __shared__ short lds[64 * 72];
  int t = threadIdx.x;
  int ij0 = blockIdx.x * 64;
  const short* src = (const short*)S_fij;
#pragma unroll
  for (int p = 0; p < 2; ++p) {
    int f = p * 32 + (t >> 3), seg = t & 7;
    short8v ga = *(const short8v*)&src[f * 262144 + ij0 + seg * 8];
    int fgrp = f >> 3, flo = f & 7;
#pragma unroll
    for (int k = 0; k < 8; ++k) {
      int ij = seg * 8 + k;
      int swz = (fgrp ^ (ij & 7) ^ ((ij >> 3) & 7)) & 7;
      lds[ij * 72 + swz * 8 + flo] = ga[k];
    }
  }
  __syncthreads();
  short* dst = (short*)S;
#pragma unroll
  for (int p = 0; p < 2; ++p) {
    int ij = p * 32 + (t >> 3), fseg = t & 7;
    int swz = (fseg ^ (ij & 7) ^ ((ij >> 3) & 7)) & 7;
    short8v val = *(const short8v*)&lds[ij * 72 + swz * 8];
    *(short8v*)&dst[(ij0 + ij) * 64 + fseg * 8] = val;
  }
}

// ------- K12: MFMA z = S@Wt + u[i]+v[j]+TW, silu, row/col/diag reduce --------
// Block = 8x8 cells (bi,bj); 4 waves; wave w owns cells w*16..w*16+15.
// A-frag: S rows (bf16, f contiguous, cell-major). B-frag: Wt in LDS.
// C layout: h = n0+(lane&15), cell = w*16 + quad*4 + reg  [m89-verified].
__global__ __launch_bounds__(256) void k_tout_mfma(
    const __hip_bfloat16* __restrict__ S, const float* __restrict__ u,
    const float* __restrict__ v, const float* __restrict__ TWc,
    const int* __restrict__ slotmap, const __hip_bfloat16* __restrict__ Wt,
    float* __restrict__ row_part, float* __restrict__ col_part,
    float* __restrict__ diag_silu) {
  __shared__ __hip_bfloat16 WtL[128 * 72];   // 18,432 B (pad 72 -> 2-way banks)
  __shared__ float uvL[2048];                // u rows | v rows, 8 KB
  __shared__ float colbuf[4][8][128];        // 16 KB
  __shared__ int slotL[64];
  int t = threadIdx.x;
  int w = t >> 6, lane = t & 63;
  int q = lane >> 4, l15 = lane & 15;
  int bi = blockIdx.x >> 6, bj = blockIdx.x & 63;
  int i0 = bi * 8, j0 = bj * 8;
  for (int e = t; e < 4096; e += 256) {
    int row = e >> 5, c2 = e & 31;
    ((unsigned*)WtL)[row * 36 + c2] = ((const unsigned*)Wt)[row * 32 + c2];
  }
  for (int e = t; e < 1024; e += 256) uvL[e] = u[(i0 + (e >> 7)) * 128 + (e & 127)];
  for (int e = t; e < 1024; e += 256) uvL[1024 + e] = v[(j0 + (e >> 7)) * 128 + (e & 127)];
  if (t < 64) slotL[t] = slotmap[(i0 + (t >> 3)) * 512 + j0 + (t & 7)];
  int cellA = w * 16 + l15;
  const short8v* sp = (const short8v*)&S[((i0 + (cellA >> 3)) * 512 + j0 + (cellA & 7)) * 64];
  short8v a0 = sp[q];
  short8v a1 = sp[4 + q];
  __syncthreads();
  v4f acc[8];
#pragma unroll
  for (int nt = 0; nt < 8; ++nt) {
    const short8v* b0 = (const short8v*)&WtL[(nt * 16 + l15) * 72 + q * 8];
    const short8v* b1 = (const short8v*)&WtL[(nt * 16 + l15) * 72 + 32 + q * 8];
    v4f c = {0.f, 0.f, 0.f, 0.f};
    c = __builtin_amdgcn_mfma_f32_16x16x32_bf16(a0, *b0, c, 0, 0, 0);
    c = __builtin_amdgcn_mfma_f32_16x16x32_bf16(a1, *b1, c, 0, 0, 0);
    acc[nt] = c;
  }
  float colp[8][4];
#pragma unroll
  for (int nt = 0; nt < 8; ++nt) {
    int hh = nt * 16 + l15;
    float rsum = 0.f;
#pragma unroll
    for (int r = 0; r < 4; ++r) {
      int c = w * 16 + q * 4 + r;
      int iL = c >> 3, jL = c & 7;
      float z = acc[nt][r] + uvL[iL * 128 + hh] + uvL[1024 + jL * 128 + hh];
      int s = slotL[c];
      if (s >= 0) z += TWc[s * 128 + hh];
      float sv = silu_f(z);
      rsum += sv;
      colp[nt][r] = sv + __shfl_xor(sv, 32);
      if (bi == bj && iL == jL) diag_silu[(i0 + iL) * 128 + hh] = sv;
    }
    rsum += __shfl_xor(rsum, 16);
    if ((q & 1) == 0)
      row_part[(bj * 512 + i0 + 2 * w + (q >> 1)) * 128 + hh] = rsum;
  }
  if (q < 2) {
#pragma unroll
    for (int nt = 0; nt < 8; ++nt)
#pragma unroll
      for (int r = 0; r < 4; ++r)
        colbuf[w][q * 4 + r][nt * 16 + l15] = colp[nt][r];
  }
  __syncthreads();
  for (int e = t; e < 1024; e += 256) {
    int jL = e >> 7, hh = e & 127;
    float a = colbuf[0][jL][hh] + colbuf[1][jL][hh] + colbuf[2][jL][hh] + colbuf[3][jL][hh];
    col_part[(bi * 512 + j0 + jL) * 128 + hh] = a;
  }
}

// ---------------- K13: reduce 64 partial slices ------------------------------
__global__ __launch_bounds__(256) void k_sumparts(
    const float* __restrict__ row_part, const float* __restrict__ col_part,
    float* __restrict__ rowsum, float* __restrict__ colsum) {
  int i = blockIdx.x, t = threadIdx.x;
  const float* src = (t < 128) ? row_part : col_part;
  float* dst = (t < 128) ? rowsum : colsum;
  int hc = t & 127;
  float a = 0.f;
  for (int p = 0; p < 64; ++p) a += src[(p * 512 + i) * 128 + hc];
  dst[i * 128 + hc] = a;
}

// ---------------- K14: second layer of p3 MLP on reduced silu sums -----------
__global__ __launch_bounds__(64) void k_tout2(
    const float* __restrict__ diag_silu, const float* __restrict__ rowsum_silu,
    const float* __restrict__ colsum_silu,
    const float* __restrict__ w2, const float* __restrict__ b2,
    float* __restrict__ diag_T, float* __restrict__ row_T, float* __restrict__ col_T) {
  __shared__ float in[128];
  int e = blockIdx.x, which = blockIdx.y, t = threadIdx.x;
  const float* src = (which == 0) ? diag_silu : (which == 1) ? rowsum_silu : colsum_silu;
  in[t] = src[e * 128 + t]; in[64 + t] = src[e * 128 + 64 + t];
  __syncthreads();
  float a = 0.f;
  for (int k = 0; k < 128; ++k) a += in[k] * w2[k * 64 + t];
  float bias = b2[t] * ((which == 0) ? 1.0f : 512.0f);
  float* dst = (which == 0) ? diag_T : (which == 1) ? row_T : col_T;
  dst[e * 64 + t] = a + bias;
}

// ---------------- K15: tot / tr ----------------------------------------------
__global__ __launch_bounds__(128) void k_totr(
    const float* __restrict__ row_T, const float* __restrict__ diag_T,
    float* __restrict__ tot, float* __restrict__ tr) {
  int t = threadIdx.x;
  const float* src = (t < 64) ? row_T : diag_T;
  int f = t & 63;
  float a = 0.f;
  for (int e = 0; e < 512; ++e) a += src[e * 64 + f];
  if (t < 64) tot[f] = a; else tr[f] = a;
}

// ---------------- K16: nb_t1 = [diag|row|col|tot|tr] @ ign_w + ign_b ---------
__global__ __launch_bounds__(64) void k_nbt1(
    const float* __restrict__ diag_T, const float* __restrict__ row_T,
    const float* __restrict__ col_T, const float* __restrict__ tot,
    const float* __restrict__ tr,
    const float* __restrict__ gw, const float* __restrict__ gb,
    float* __restrict__ nb_t1) {
  __shared__ float in[320];
  int e = blockIdx.x, t = threadIdx.x;
  in[t] = diag_T[e * 64 + t]; in[64 + t] = row_T[e * 64 + t];
  in[128 + t] = col_T[e * 64 + t]; in[192 + t] = tot[t]; in[256 + t] = tr[t];
  __syncthreads();
  float a = gb[t];
  for (int k = 0; k < 320; ++k) a += in[k] * gw[k * 64 + t];
  nb_t1[e * 64 + t] = a;
}

// ----- K17: coord weight w_e, seg/cnt/nb_t0 scatters, edge_attr passthrough --
__global__ __launch_bounds__(128) void k_edge_out(
    const int* __restrict__ edges, const float* __restrict__ coord_diff,
    const float* __restrict__ nb_t1, const float* __restrict__ edge_attr,
    const float* __restrict__ cw1, const float* __restrict__ cb1,
    const float* __restrict__ cw2,
    float* __restrict__ seg, float* __restrict__ cnt, float* __restrict__ nb_t0,
    float* __restrict__ out_ea) {
  __shared__ float in[64];
  __shared__ float red[128];
  int e = blockIdx.x, t = threadIdx.x;
  if (t < 64) in[t] = nb_t1[e * 64 + t];
  __syncthreads();
  float a = cb1[t];
  for (int k = 0; k < 64; ++k) a += in[k] * cw1[k * 128 + t];
  red[t] = silu_f(a) * cw2[t];
  __syncthreads();
  for (int s2 = 64; s2 > 0; s2 >>= 1) {
    if (t < s2) red[t] += red[t + s2];
    __syncthreads();
  }
  float w = red[0];
  int r = edges[e];
  if (t < 3) atomicAdd(&seg[r * 3 + t], coord_diff[e * 3 + t] * w);
  if (t == 64) atomicAdd(&cnt[r], 1.0f);
  if (t < 64) atomicAdd(&nb_t0[r * 64 + t], in[t]);
  if (t < 4) out_ea[e * 4 + t] = edge_attr[e * 4 + t];
}

// ---------------- K18: x_new and h_new ---------------------------------------
__global__ __launch_bounds__(128) void k_node_out(
    const float* __restrict__ h, const float* __restrict__ x,
    const float* __restrict__ seg, const float* __restrict__ cnt,
    const float* __restrict__ nb_t0,
    const float* __restrict__ w1, const float* __restrict__ b1,
    const float* __restrict__ w2, const float* __restrict__ b2,
    float* __restrict__ out_h, float* __restrict__ out_x) {
  __shared__ float in[64];
  __shared__ float hs[128];
  int n = blockIdx.x, t = threadIdx.x;
  if (t < 3) {
    float c = cnt[n]; if (c < 1.f) c = 1.f;
    out_x[n * 3 + t] = x[n * 3 + t] + seg[n * 3 + t] / c;
  }
  if (t < 64) in[t] = nb_t0[n * 64 + t];
  __syncthreads();
  float a = b1[t];
  for (int k = 0; k < 64; ++k) a += in[k] * w1[k * 128 + t];
  hs[t] = silu_f(a);
  __syncthreads();
  if (t < 64) {
    float o = b2[t];
    for (int k = 0; k < 128; ++k) o += hs[k] * w2[k * 64 + t];
    out_h[n * 64 + t] = h[n * 64 + t] + o;
  }
}

extern "C" void kernel_launch(void* const* d_in, const int* in_sizes, int n_in,
                              void* d_out, int out_size, void* d_ws, size_t ws_size,
                              hipStream_t stream) {
  (void)in_sizes; (void)n_in; (void)out_size; (void)ws_size;
  const float* h  = (const float*)d_in[0];
  const float* x  = (const float*)d_in[1];
  const int* edges   = (const int*)d_in[2];
  const int* nb_edge = (const int*)d_in[3];
  const float* edge_attr = (const float*)d_in[4];
  const float* ew1 = (const float*)d_in[6],  *eb1 = (const float*)d_in[7];
  const float* ew2 = (const float*)d_in[8],  *eb2 = (const float*)d_in[9];
  const float* p1w1 = (const float*)d_in[10], *p1b1 = (const float*)d_in[11];
  const float* p1w2 = (const float*)d_in[12], *p1b2 = (const float*)d_in[13];
  const float* p2w1 = (const float*)d_in[14], *p2b1 = (const float*)d_in[15];
  const float* p2w2 = (const float*)d_in[16], *p2b2 = (const float*)d_in[17];
  const float* p3w1 = (const float*)d_in[18], *p3b1 = (const float*)d_in[19];
  const float* p3w2 = (const float*)d_in[20], *p3b2 = (const float*)d_in[21];
  const float* ignw = (const float*)d_in[22], *ignb = (const float*)d_in[23];
  const float* cw1 = (const float*)d_in[24], *cb1 = (const float*)d_in[25];
  const float* cw2 = (const float*)d_in[26];
  const float* ndw1 = (const float*)d_in[27], *ndb1 = (const float*)d_in[28];
  const float* ndw2 = (const float*)d_in[29], *ndb2 = (const float*)d_in[30];

  // ---- workspace layout (~162 MB) ----
  char* ws = (char*)d_ws;
  __hip_bfloat16* D1d  = (__hip_bfloat16*)(ws + 0);          // [64][512][512] = 33,554,432 B
  __hip_bfloat16* S    = (__hip_bfloat16*)(ws + 0);          // cell-major S aliases dead D1d
  __hip_bfloat16* D2dT = (__hip_bfloat16*)(ws + 33554432);   // 33,554,432 B
  __hip_bfloat16* S_fij = (__hip_bfloat16*)(ws + 67108864);  // 33,554,432 B
  float* row_part = (float*)(ws + 100663296);                // [64][512][128] = 16,777,216 B
  float* col_part = (float*)(ws + 117440512);                // 16,777,216 B
  // ---- single zero-memset block [134,217,728 .. 140,910,608) ----
  float* Tc    = (float*)(ws + 134217728);                   // [16384][96] = 6,291,456 B
  int*   nC    = (int*)(ws + 140509184);                     // 1 int (+pad to 16)
  float* A     = (float*)(ws + 140509200);                   // 32768 floats
  float* B     = (float*)(ws + 140640272);                   // 32768 floats
  float* seg   = (float*)(ws + 140771344);                   // 1536 floats
  float* cnt   = (float*)(ws + 140777488);                   // 512 floats
  float* nb_t0 = (float*)(ws + 140779536);                   // 32768 floats -> end 140,910,608
  // ---- rest ----
  int*   slotmap  = (int*)(ws + 140910608);                  // 262144 ints (0xFF)
  int*   slotmapT = (int*)(ws + 141959184);                  // 262144 ints (0xFF)
  int*   cells    = (int*)(ws + 143007760);                  // 16384 ints
  float* D1       = (float*)(ws + 143073296);                // [16384][64]
  float* D2       = (float*)(ws + 147267600);                // [16384][64]
  float* TWc      = (float*)(ws + 151461904);                // [16384][128]
  float* c1       = (float*)(ws + 159850512);                // 64
  float* c2       = (float*)(ws + 159850768);                // 64
  float* u        = (float*)(ws + 159851024);                // [512][128]
  float* v        = (float*)(ws + 160113168);                // [512][128]
  float* coord_diff  = (float*)(ws + 160375312);             // [512][3]
  float* efn         = (float*)(ws + 160381456);             // [512][64]
  float* diag_silu   = (float*)(ws + 160512528);             // [512][128]
  float* rowsum_silu = (float*)(ws + 160774672);
  float* colsum_silu = (float*)(ws + 161036816);
  float* diag_T      = (float*)(ws + 161298960);             // [512][64]
  float* row_T       = (float*)(ws + 161430032);
  float* col_T       = (float*)(ws + 161561104);
  float* tot         = (float*)(ws + 161692176);             // 64
  float* tr          = (float*)(ws + 161692432);             // 64
  float* nb_t1       = (float*)(ws + 161692688);             // [512][64]
  __hip_bfloat16* Wt = (__hip_bfloat16*)(ws + 161823760);    // [128][64] -> end 161,840,144

  float* out_h  = (float*)d_out;
  float* out_x  = out_h + 512 * 64;
  float* out_ea = out_x + 512 * 3;

  hipMemsetAsync(slotmap, 0xFF, 2097152, stream);            // slotmap + slotmapT = -1
  hipMemsetAsync(ws + 134217728, 0, 6692880, stream);        // Tc..nb_t0

  k_edge<<<512, 128, 0, stream>>>(h, x, edges, ew1, eb1, ew2, eb2, coord_diff, efn);
  k_consts<<<1, 128, 0, stream>>>(p1b1, p1w2, p1b2, p2b1, p2w2, p2b2, c1, c2);
  k_prep<<<32, 256, 0, stream>>>(p3w1, Wt);
  k_mark<<<64, 256, 0, stream>>>(nb_edge, slotmap);
  k_compact<<<1024, 256, 0, stream>>>(slotmap, slotmapT, cells, nC);
  k_scatterT<<<8192, 192, 0, stream>>>(nb_edge, slotmap, coord_diff, efn, Tc);
  k_mlp96b<<<2048, 128, 0, stream>>>(cells, nC, Tc,
                                     p1w1, p1b1, p1w2, p1b2,
                                     p2w1, p2b1, p2w2, p2b2,
                                     c1, c2, p3w1, D1, D2, A, B, TWc);
  k_uv<<<dim3(512, 2), 128, 0, stream>>>(A, B, c1, c2, p3w1, p3b1, u, v);
  k_densify<<<dim3(512, 128), 512, 0, stream>>>(slotmap, slotmapT, D1, D2, D1d, D2dT);
  k_einsum_mfma<<<1024, 256, 0, stream>>>(D1d, D2dT, S_fij);
  k_transpose<<<4096, 256, 0, stream>>>(S_fij, S);
  k_tout_mfma<<<4096, 256, 0, stream>>>(S, u, v, TWc, slotmap, Wt,
                                        row_part, col_part, diag_silu);
  k_sumparts<<<512, 256, 0, stream>>>(row_part, col_part, rowsum_silu, colsum_silu);
  k_tout2<<<dim3(512, 3), 64, 0, stream>>>(diag_silu, rowsum_silu, colsum_silu,
                                           p3w2, p3b2, diag_T, row_T, col_T);
  k_totr<<<1, 128, 0, stream>>>(row_T, diag_T, tot, tr);
  k_nbt1<<<512, 64, 0, stream>>>(diag_T, row_T, col_T, tot, tr, ignw, ignb, nb_t1);
  k_edge_out<<<512, 128, 0, stream>>>(edges, coord_diff, nb_t1, edge_attr,
                                      cw1, cb1, cw2, seg, cnt, nb_t0, out_ea);
  k_node_out<<<512, 128, 0, stream>>>(h, x, seg, cnt, nb_t0,
                                      ndw1, ndb1, ndw2, ndb2, out_h, out_x);
}

// Round 12
// 443.274 us; speedup vs baseline: 1.1394x; 1.0256x over previous
//
#include <hip/hip_runtime.h>
#include <hip/hip_bf16.h>

// Problem constants (static per reference)
#define NN   512    // nodes
#define EE   512    // edges == nb-graph nodes (En)
#define MM   16384  // nb-graph edges

typedef float v4f __attribute__((ext_vector_type(4)));
typedef short short8v __attribute__((ext_vector_type(8)));

__device__ __forceinline__ float silu_f(float v) { return v / (1.0f + __expf(-v)); }

// ---------------- K1: per original edge: coord_diff + efn = MLP([h_r|h_c]) ----
__global__ __launch_bounds__(128) void k_edge(
    const float* __restrict__ h, const float* __restrict__ x,
    const int* __restrict__ edges,
    const float* __restrict__ ew1, const float* __restrict__ eb1,
    const float* __restrict__ ew2, const float* __restrict__ eb2,
    float* __restrict__ coord_diff, float* __restrict__ efn) {
  __shared__ float hin[128];
  __shared__ float hs[128];
  int e = blockIdx.x;
  int t = threadIdx.x;
  int r = edges[e], c = edges[EE + e];
  if (t < 3) coord_diff[e * 3 + t] = x[r * 3 + t] - x[c * 3 + t];
  if (t < 64) { hin[t] = h[r * 64 + t]; hin[64 + t] = h[c * 64 + t]; }
  __syncthreads();
  float acc = eb1[t];
  for (int k = 0; k < 128; ++k) acc += hin[k] * ew1[k * 128 + t];
  hs[t] = silu_f(acc);
  __syncthreads();
  if (t < 64) {
    float o = eb2[t];
    for (int k = 0; k < 128; ++k) o += hs[k] * ew2[k * 64 + t];
    efn[e * 64 + t] = o;
  }
}

// ---------------- K2: constants c1 = MLP1(0), c2 = MLP2(0) -------------------
__global__ __launch_bounds__(128) void k_consts(
    const float* __restrict__ p1b1, const float* __restrict__ p1w2, const float* __restrict__ p1b2,
    const float* __restrict__ p2b1, const float* __restrict__ p2w2, const float* __restrict__ p2b2,
    float* __restrict__ c1, float* __restrict__ c2) {
  __shared__ float h1[128], h2[128];
  int t = threadIdx.x;
  h1[t] = silu_f(p1b1[t]); h2[t] = silu_f(p2b1[t]);
  __syncthreads();
  if (t < 64) {
    float a1 = p1b2[t], a2 = p2b2[t];
    for (int k = 0; k < 128; ++k) { a1 += h1[k] * p1w2[k * 64 + t]; a2 += h2[k] * p2w2[k * 64 + t]; }
    c1[t] = a1; c2[t] = a2;
  }
}

// ---------------- K2b: Wt[h][f] = bf16(p3w1[96+f][h]) (B-operand for MFMA) ---
__global__ __launch_bounds__(256) void k_prep(const float* __restrict__ p3w1,
                                              __hip_bfloat16* __restrict__ Wt) {
  int e = blockIdx.x * 256 + threadIdx.x;   // 8192 = 128 h x 64 f
  int hh = e >> 6, f = e & 63;
  Wt[hh * 64 + f] = __float2bfloat16(p3w1[(96 + f) * 128 + hh]);
}

// ---------------- K3: mark touched cells -------------------------------------
__global__ __launch_bounds__(256) void k_mark(const int* __restrict__ nb_edge,
                                              int* __restrict__ slotmap) {
  int m = blockIdx.x * 256 + threadIdx.x;
  if (m >= MM) return;
  int cell = nb_edge[m] * 512 + nb_edge[MM + m];
  atomicCAS(&slotmap[cell], -1, -2);
}

// ------ K4: compact marked cells -> slots (both orientations) ----------------
__global__ __launch_bounds__(256) void k_compact(int* __restrict__ slotmap,
                                                 int* __restrict__ slotmapT,
                                                 int* __restrict__ cells,
                                                 int* __restrict__ nC) {
  int cell = blockIdx.x * 256 + threadIdx.x;
  if (slotmap[cell] != -2) return;
  int s = atomicAdd(nC, 1);
  slotmap[cell] = s;
  slotmapT[(cell & 511) * 512 + (cell >> 9)] = s;
  cells[s] = cell;
}

// ---------------- K7: nb_feat scatter-add into COMPACT Tc (2 edges/block) ----
__global__ __launch_bounds__(192) void k_scatterT(
    const int* __restrict__ nb_edge, const int* __restrict__ slotmap,
    const float* __restrict__ coord_diff, const float* __restrict__ efn,
    float* __restrict__ Tc) {
  int t = threadIdx.x;
  int sub = (t >= 96) ? 1 : 0;
  int c = t - sub * 96;
  int m = blockIdx.x * 2 + sub;
  int a = nb_edge[m], b = nb_edge[MM + m];
  int s = slotmap[a * 512 + b];
  float val;
  if (c < 32) {
    float vtv = coord_diff[a * 3 + 0] * coord_diff[b * 3 + 0]
              + coord_diff[a * 3 + 1] * coord_diff[b * 3 + 1]
              + coord_diff[a * 3 + 2] * coord_diff[b * 3 + 2];
    int i = c >> 1;
    float ang = vtv * 16.0f * __expf(-0.57564627324851143f * (float)i);
    val = (c & 1) ? cosf(ang) : sinf(ang);
  } else {
    int f = c - 32;
    val = efn[a * 64 + f] * efn[b * 64 + f];
  }
  atomicAdd(&Tc[s * 96 + c], val);
}

// ------- K8: batched (8 cells/block) MLPs -> D1/D2, sums A,B; TWc = Tc@w1T ---
__global__ __launch_bounds__(128) void k_mlp96b(
    const int* __restrict__ cells, const int* __restrict__ nC, const float* __restrict__ Tc,
    const float* __restrict__ w11, const float* __restrict__ b11,
    const float* __restrict__ w12, const float* __restrict__ b12,
    const float* __restrict__ w21, const float* __restrict__ b21,
    const float* __restrict__ w22, const float* __restrict__ b22,
    const float* __restrict__ c1, const float* __restrict__ c2,
    const float* __restrict__ p3w1,
    float* __restrict__ D1, float* __restrict__ D2,
    float* __restrict__ A, float* __restrict__ B,
    float* __restrict__ TWc) {
  __shared__ float xsT[96 * 8];    // [k][cell] transposed for b128 reads
  __shared__ float hid[8][128];
  __shared__ int cl[8];
  int t = threadIdx.x;
  int nc = *nC;
  int s0 = blockIdx.x * 8;
  if (s0 >= nc) return;
  for (int e = t; e < 768; e += 128) xsT[(e % 96) * 8 + e / 96] = Tc[s0 * 96 + e];
  if (t < 8) cl[t] = (s0 + t < nc) ? cells[s0 + t] : 0;
  __syncthreads();
  float tw[8], a1[8], a2[8];
#pragma unroll
  for (int c = 0; c < 8; ++c) { tw[c] = 0.f; a1[c] = b11[t]; a2[c] = b21[t]; }
  for (int k = 0; k < 96; ++k) {
    float wt = p3w1[k * 128 + t];
    float w1v = w11[k * 128 + t];
    float w2v = w21[k * 128 + t];
    float4 xlo = *(const float4*)&xsT[k * 8];
    float4 xhi = *(const float4*)&xsT[k * 8 + 4];
    float xv[8] = {xlo.x, xlo.y, xlo.z, xlo.w, xhi.x, xhi.y, xhi.z, xhi.w};
#pragma unroll
    for (int c = 0; c < 8; ++c) {
      tw[c] += xv[c] * wt; a1[c] += xv[c] * w1v; a2[c] += xv[c] * w2v;
    }
  }
#pragma unroll
  for (int c = 0; c < 8; ++c) {
    if (s0 + c < nc) TWc[(s0 + c) * 128 + t] = tw[c];
    hid[c][t] = silu_f(a1[c]);
  }
  __syncthreads();
  {
    int hh = t & 63, cq = t >> 6;
    float o[4];
#pragma unroll
    for (int cc = 0; cc < 4; ++cc) o[cc] = b12[hh];
    for (int k = 0; k < 128; ++k) {
      float w = w12[k * 64 + hh];
#pragma unroll
      for (int cc = 0; cc < 4; ++cc) o[cc] += hid[cq * 4 + cc][k] * w;
    }
#pragma unroll
    for (int cc = 0; cc < 4; ++cc) {
      int c = cq * 4 + cc;
      if (s0 + c < nc) {
        float d = o[cc] - c1[hh];
        D1[(s0 + c) * 64 + hh] = d;
        atomicAdd(&A[(cl[c] >> 9) * 64 + hh], d);
      }
    }
  }
  __syncthreads();
#pragma unroll
  for (int c = 0; c < 8; ++c) hid[c][t] = silu_f(a2[c]);
  __syncthreads();
  {
    int hh = t & 63, cq = t >> 6;
    float o[4];
#pragma unroll
    for (int cc = 0; cc < 4; ++cc) o[cc] = b22[hh];
    for (int k = 0; k < 128; ++k) {
      float w = w22[k * 64 + hh];
#pragma unroll
      for (int cc = 0; cc < 4; ++cc) o[cc] += hid[cq * 4 + cc][k] * w;
    }
#pragma unroll
    for (int cc = 0; cc < 4; ++cc) {
      int c = cq * 4 + cc;
      if (s0 + c < nc) {
        float d = o[cc] - c2[hh];
        D2[(s0 + c) * 64 + hh] = d;
        atomicAdd(&B[(cl[c] & 511) * 64 + hh], d);
      }
    }
  }
}

// ---------------- K10: u[i] = b1 + (512 c1c2 + c2*A[i])@w1m ; v[j] = (c1*B[j])@w1m
__global__ __launch_bounds__(128) void k_uv(
    const float* __restrict__ A, const float* __restrict__ B,
    const float* __restrict__ c1, const float* __restrict__ c2,
    const float* __restrict__ p3w1, const float* __restrict__ p3b1,
    float* __restrict__ u, float* __restrict__ v) {
  __shared__ float vec[64];
  int i = blockIdx.x, y = blockIdx.y, t = threadIdx.x;
  if (t < 64)
    vec[t] = (y == 0) ? (512.0f * c1[t] * c2[t] + c2[t] * A[i * 64 + t])
                      : (c1[t] * B[i * 64 + t]);
  __syncthreads();
  float a = (y == 0) ? p3b1[t] : 0.f;
  for (int f = 0; f < 64; ++f) a += vec[f] * p3w1[(96 + f) * 128 + t];
  (y == 0 ? u : v)[i * 128 + t] = a;
}

// ---------------- K11a: densify compact D1/D2 into plane-major bf16 ----------
__global__ __launch_bounds__(512) void k_densify(
    const int* __restrict__ slotmap, const int* __restrict__ slotmapT,
    const float* __restrict__ D1, const float* __restrict__ D2,
    __hip_bfloat16* __restrict__ D1d, __hip_bfloat16* __restrict__ D2dT) {
  int k = threadIdx.x;
  int i = blockIdx.x;
  int y = blockIdx.y;
  if (y < 64) {
    int f = y;
    int s = slotmap[i * 512 + k];
    float v = (s >= 0) ? D1[s * 64 + f] : 0.f;
    D1d[(f * 512 + i) * 512 + k] = __float2bfloat16(v);
  } else {
    int f = y - 64;
    int s = slotmapT[i * 512 + k];
    float v = (s >= 0) ? D2[s * 64 + f] : 0.f;
    D2dT[(f * 512 + i) * 512 + k] = __float2bfloat16(v);
  }
}

// ---------------- K11b: batched plane GEMM S_f = A_f * B_f (MFMA) ------------
__global__ __launch_bounds__(256) void k_einsum_mfma(
    const __hip_bfloat16* __restrict__ D1d,
    const __hip_bfloat16* __restrict__ D2dT,
    __hip_bfloat16* __restrict__ S_fij) {
  __shared__ short As[128 * 40];
  __shared__ short Bs[128 * 40];
  int b = blockIdx.x;
  int f = b >> 4;
  int i0 = ((b >> 2) & 3) * 128, j0 = (b & 3) * 128;
  int t = threadIdx.x;
  int w = t >> 6, lane = t & 63;
  int wy = w >> 1, wx = w & 1;
  int q = lane >> 4, l15 = lane & 15;
  const short* Ap = (const short*)D1d + f * 262144;
  const short* Bp = (const short*)D2dT + f * 262144;
  int row = t >> 1, seg = t & 1;   // staging: 128 rows x 2 segments of 16
  v4f acc[4][4];
#pragma unroll
  for (int yi = 0; yi < 4; ++yi)
#pragma unroll
    for (int xj = 0; xj < 4; ++xj) acc[yi][xj] = (v4f){0.f, 0.f, 0.f, 0.f};
  for (int k0 = 0; k0 < 512; k0 += 32) {
    __syncthreads();
    const short8v* ga = (const short8v*)&Ap[(i0 + row) * 512 + k0 + seg * 16];
    const short8v* gb = (const short8v*)&Bp[(j0 + row) * 512 + k0 + seg * 16];
    *(short8v*)&As[row * 40 + seg * 16] = ga[0];
    *(short8v*)&As[row * 40 + seg * 16 + 8] = ga[1];
    *(short8v*)&Bs[row * 40 + seg * 16] = gb[0];
    *(short8v*)&Bs[row * 40 + seg * 16 + 8] = gb[1];
    __syncthreads();
    short8v af[4], bf[4];
#pragma unroll
    for (int x = 0; x < 4; ++x) {
      af[x] = *(const short8v*)&As[(wy * 64 + x * 16 + l15) * 40 + q * 8];
      bf[x] = *(const short8v*)&Bs[(wx * 64 + x * 16 + l15) * 40 + q * 8];
    }
#pragma unroll
    for (int yi = 0; yi < 4; ++yi)
#pragma unroll
      for (int xj = 0; xj < 4; ++xj)
        acc[yi][xj] = __builtin_amdgcn_mfma_f32_16x16x32_bf16(af[yi], bf[xj], acc[yi][xj], 0, 0, 0);
  }
  // C layout: col j = l15, row i = q*4 + r  [m89-verified]
#pragma unroll
  for (int yi = 0; yi < 4; ++yi)
#pragma unroll
    for (int r = 0; r < 4; ++r) {
      int irow = i0 + wy * 64 + yi * 16 + q * 4 + r;
#pragma unroll
      for (int xj = 0; xj < 4; ++xj)
        S_fij[(f * 512 + irow) * 512 + j0 + wx * 64 + xj * 16 + l15] =
            __float2bfloat16(acc[yi][xj][r]);
    }
}

// ---------------- K11c: transpose S_fij [64][262144] -> S [262144][64] -------
__global__ __launch_bounds__(256) void k_transpose(
    const __hip_bfloat16* __restrict__ S_fij, __hip_bfloat16* __restrict__ S) {
  __shared__ short lds[64 * 72];
  int t = threadIdx.x;
  int ij0 = blockIdx.x * 64;
  const short* src = (const short*)S_fij;
#pragma unroll
  for (int p = 0; p < 2; ++p) {
    int f = p * 32 + (t >> 3), seg = t & 7;
    short8v ga = *(const short8v*)&src[f * 262144 + ij0 + seg * 8];
    int fgrp = f >> 3, flo = f & 7;
#pragma unroll
    for (int k = 0; k < 8; ++k) {
      int ij = seg * 8 + k;
      int swz = (fgrp ^ (ij & 7) ^ ((ij >> 3) & 7)) & 7;
      lds[ij * 72 + swz * 8 + flo] = ga[k];
    }
  }
  __syncthreads();
  short* dst = (short*)S;
#pragma unroll
  for (int p = 0; p < 2; ++p) {
    int ij = p * 32 + (t >> 3), fseg = t & 7;
    int swz = (fseg ^ (ij & 7) ^ ((ij >> 3) & 7)) & 7;
    short8v val = *(const short8v*)&lds[ij * 72 + swz * 8];
    *(short8v*)&dst[(ij0 + ij) * 64 + fseg * 8] = val;
  }
}

// ------- K12: MFMA z = S@Wt + u[i]+v[j]+TW, silu, row/col/diag reduce --------
// v3: 16x16-cell tile (grid 1024 = 32x32 blocks); 4 waves; wave w owns rows
// iL = w*4..w*4+3. M-tile mt = one row i x 16 j; N = h (2 halves of 4 N-tiles
// to cap acc VGPR at 64). C layout [m89]: n(h) = l15, m = q*4+r -> jL = q*4+r.
__global__ __launch_bounds__(256) void k_tout_mfma(
    const __hip_bfloat16* __restrict__ S, const float* __restrict__ u,
    const float* __restrict__ v, const float* __restrict__ TWc,
    const int* __restrict__ slotmap, const __hip_bfloat16* __restrict__ Wt,
    float* __restrict__ row_part, float* __restrict__ col_part,
    float* __restrict__ diag_silu) {
  __shared__ __hip_bfloat16 WtL[128 * 72];     // 18,432 B
  __shared__ float uvL[4096];                  // u 16x128 | v 16x128, 16 KB
  __shared__ float colbuf[4][16][128];         // 32 KB (per-wave private planes)
  __shared__ int slotL[256];
  int t = threadIdx.x;
  int w = t >> 6, lane = t & 63;
  int q = lane >> 4, l15 = lane & 15;
  int bi = blockIdx.x >> 5, bj = blockIdx.x & 31;
  int i0 = bi * 16, j0 = bj * 16;
  for (int e = t; e < 4096; e += 256) {
    int row = e >> 5, c2 = e & 31;
    ((unsigned*)WtL)[row * 36 + c2] = ((const unsigned*)Wt)[row * 32 + c2];
  }
  for (int e = t; e < 2048; e += 256) uvL[e] = u[(i0 + (e >> 7)) * 128 + (e & 127)];
  for (int e = t; e < 2048; e += 256) uvL[2048 + e] = v[(j0 + (e >> 7)) * 128 + (e & 127)];
  slotL[t] = slotmap[(i0 + (t >> 4)) * 512 + j0 + (t & 15)];
  // A-frags: M-tile mt = row i0+w*4+mt, cols j0..j0+15 (lane l15 = jL)
  short8v a[4][2];
#pragma unroll
  for (int mt = 0; mt < 4; ++mt) {
    const short8v* sp =
        (const short8v*)&S[((i0 + w * 4 + mt) * 512 + j0 + l15) * 64];
    a[mt][0] = sp[q];
    a[mt][1] = sp[4 + q];
  }
  __syncthreads();
#pragma unroll
  for (int half = 0; half < 2; ++half) {
    v4f acc[4][4];
#pragma unroll
    for (int mt = 0; mt < 4; ++mt)
#pragma unroll
      for (int n4 = 0; n4 < 4; ++n4) {
        int nt = half * 4 + n4;
        const short8v* b0 = (const short8v*)&WtL[(nt * 16 + l15) * 72 + q * 8];
        const short8v* b1 = (const short8v*)&WtL[(nt * 16 + l15) * 72 + 32 + q * 8];
        v4f c = {0.f, 0.f, 0.f, 0.f};
        c = __builtin_amdgcn_mfma_f32_16x16x32_bf16(a[mt][0], *b0, c, 0, 0, 0);
        c = __builtin_amdgcn_mfma_f32_16x16x32_bf16(a[mt][1], *b1, c, 0, 0, 0);
        acc[mt][n4] = c;
      }
#pragma unroll
    for (int n4 = 0; n4 < 4; ++n4) {
      int nt = half * 4 + n4;
      int hh = nt * 16 + l15;
      float rs[4] = {0.f, 0.f, 0.f, 0.f};
#pragma unroll
      for (int r = 0; r < 4; ++r) {
        int jL = q * 4 + r;
        float cs = 0.f;
        float vv = uvL[2048 + jL * 128 + hh];
#pragma unroll
        for (int mt = 0; mt < 4; ++mt) {
          int iL = w * 4 + mt;
          float z = acc[mt][n4][r] + uvL[iL * 128 + hh] + vv;
          int s = slotL[iL * 16 + jL];
          if (s >= 0) z += TWc[s * 128 + hh];
          float sv = silu_f(z);
          rs[mt] += sv;
          cs += sv;
          if (bi == bj && iL == jL) diag_silu[(i0 + iL) * 128 + hh] = sv;
        }
        colbuf[w][jL][hh] = cs;   // per-wave plane; unique (jL,hh) per lane
      }
#pragma unroll
      for (int mt = 0; mt < 4; ++mt) {
        float rsum = rs[mt];
        rsum += __shfl_xor(rsum, 16);
        rsum += __shfl_xor(rsum, 32);
        if (q == 0)
          row_part[(bj * 512 + i0 + w * 4 + mt) * 128 + hh] = rsum;
      }
    }
  }
  __syncthreads();
  for (int e = t; e < 2048; e += 256) {
    int jL = e >> 7, hh = e & 127;
    float acc4 = colbuf[0][jL][hh] + colbuf[1][jL][hh] +
                 colbuf[2][jL][hh] + colbuf[3][jL][hh];
    col_part[(bi * 512 + j0 + jL) * 128 + hh] = acc4;
  }
}

// ---------------- K13: reduce 32 partial slices ------------------------------
__global__ __launch_bounds__(256) void k_sumparts(
    const float* __restrict__ row_part, const float* __restrict__ col_part,
    float* __restrict__ rowsum, float* __restrict__ colsum) {
  int i = blockIdx.x, t = threadIdx.x;
  const float* src = (t < 128) ? row_part : col_part;
  float* dst = (t < 128) ? rowsum : colsum;
  int hc = t & 127;
  float a = 0.f;
  for (int p = 0; p < 32; ++p) a += src[(p * 512 + i) * 128 + hc];
  dst[i * 128 + hc] = a;
}

// ---------------- K14: second layer of p3 MLP on reduced silu sums -----------
__global__ __launch_bounds__(64) void k_tout2(
    const float* __restrict__ diag_silu, const float* __restrict__ rowsum_silu,
    const float* __restrict__ colsum_silu,
    const float* __restrict__ w2, const float* __restrict__ b2,
    float* __restrict__ diag_T, float* __restrict__ row_T, float* __restrict__ col_T) {
  __shared__ float in[128];
  int e = blockIdx.x, which = blockIdx.y, t = threadIdx.x;
  const float* src = (which == 0) ? diag_silu : (which == 1) ? rowsum_silu : colsum_silu;
  in[t] = src[e * 128 + t]; in[64 + t] = src[e * 128 + 64 + t];
  __syncthreads();
  float a = 0.f;
  for (int k = 0; k < 128; ++k) a += in[k] * w2[k * 64 + t];
  float bias = b2[t] * ((which == 0) ? 1.0f : 512.0f);
  float* dst = (which == 0) ? diag_T : (which == 1) ? row_T : col_T;
  dst[e * 64 + t] = a + bias;
}

// ---------------- K15: tot / tr ----------------------------------------------
__global__ __launch_bounds__(128) void k_totr(
    const float* __restrict__ row_T, const float* __restrict__ diag_T,
    float* __restrict__ tot, float* __restrict__ tr) {
  int t = threadIdx.x;
  const float* src = (t < 64) ? row_T : diag_T;
  int f = t & 63;
  float a = 0.f;
  for (int e = 0; e < 512; ++e) a += src[e * 64 + f];
  if (t < 64) tot[f] = a; else tr[f] = a;
}

// ---------------- K16: nb_t1 = [diag|row|col|tot|tr] @ ign_w + ign_b ---------
__global__ __launch_bounds__(64) void k_nbt1(
    const float* __restrict__ diag_T, const float* __restrict__ row_T,
    const float* __restrict__ col_T, const float* __restrict__ tot,
    const float* __restrict__ tr,
    const float* __restrict__ gw, const float* __restrict__ gb,
    float* __restrict__ nb_t1) {
  __shared__ float in[320];
  int e = blockIdx.x, t = threadIdx.x;
  in[t] = diag_T[e * 64 + t]; in[64 + t] = row_T[e * 64 + t];
  in[128 + t] = col_T[e * 64 + t]; in[192 + t] = tot[t]; in[256 + t] = tr[t];
  __syncthreads();
  float a = gb[t];
  for (int k = 0; k < 320; ++k) a += in[k] * gw[k * 64 + t];
  nb_t1[e * 64 + t] = a;
}

// ----- K17: coord weight w_e, seg/cnt/nb_t0 scatters, edge_attr passthrough --
__global__ __launch_bounds__(128) void k_edge_out(
    const int* __restrict__ edges, const float* __restrict__ coord_diff,
    const float* __restrict__ nb_t1, const float* __restrict__ edge_attr,
    const float* __restrict__ cw1, const float* __restrict__ cb1,
    const float* __restrict__ cw2,
    float* __restrict__ seg, float* __restrict__ cnt, float* __restrict__ nb_t0,
    float* __restrict__ out_ea) {
  __shared__ float in[64];
  __shared__ float red[128];
  int e = blockIdx.x, t = threadIdx.x;
  if (t < 64) in[t] = nb_t1[e * 64 + t];
  __syncthreads();
  float a = cb1[t];
  for (int k = 0; k < 64; ++k) a += in[k] * cw1[k * 128 + t];
  red[t] = silu_f(a) * cw2[t];
  __syncthreads();
  for (int s2 = 64; s2 > 0; s2 >>= 1) {
    if (t < s2) red[t] += red[t + s2];
    __syncthreads();
  }
  float w = red[0];
  int r = edges[e];
  if (t < 3) atomicAdd(&seg[r * 3 + t], coord_diff[e * 3 + t] * w);
  if (t == 64) atomicAdd(&cnt[r], 1.0f);
  if (t < 64) atomicAdd(&nb_t0[r * 64 + t], in[t]);
  if (t < 4) out_ea[e * 4 + t] = edge_attr[e * 4 + t];
}

// ---------------- K18: x_new and h_new ---------------------------------------
__global__ __launch_bounds__(128) void k_node_out(
    const float* __restrict__ h, const float* __restrict__ x,
    const float* __restrict__ seg, const float* __restrict__ cnt,
    const float* __restrict__ nb_t0,
    const float* __restrict__ w1, const float* __restrict__ b1,
    const float* __restrict__ w2, const float* __restrict__ b2,
    float* __restrict__ out_h, float* __restrict__ out_x) {
  __shared__ float in[64];
  __shared__ float hs[128];
  int n = blockIdx.x, t = threadIdx.x;
  if (t < 3) {
    float c = cnt[n]; if (c < 1.f) c = 1.f;
    out_x[n * 3 + t] = x[n * 3 + t] + seg[n * 3 + t] / c;
  }
  if (t < 64) in[t] = nb_t0[n * 64 + t];
  __syncthreads();
  float a = b1[t];
  for (int k = 0; k < 64; ++k) a += in[k] * w1[k * 128 + t];
  hs[t] = silu_f(a);
  __syncthreads();
  if (t < 64) {
    float o = b2[t];
    for (int k = 0; k < 128; ++k) o += hs[k] * w2[k * 64 + t];
    out_h[n * 64 + t] = h[n * 64 + t] + o;
  }
}

extern "C" void kernel_launch(void* const* d_in, const int* in_sizes, int n_in,
                              void* d_out, int out_size, void* d_ws, size_t ws_size,
                              hipStream_t stream) {
  (void)in_sizes; (void)n_in; (void)out_size; (void)ws_size;
  const float* h  = (const float*)d_in[0];
  const float* x  = (const float*)d_in[1];
  const int* edges   = (const int*)d_in[2];
  const int* nb_edge = (const int*)d_in[3];
  const float* edge_attr = (const float*)d_in[4];
  const float* ew1 = (const float*)d_in[6],  *eb1 = (const float*)d_in[7];
  const float* ew2 = (const float*)d_in[8],  *eb2 = (const float*)d_in[9];
  const float* p1w1 = (const float*)d_in[10], *p1b1 = (const float*)d_in[11];
  const float* p1w2 = (const float*)d_in[12], *p1b2 = (const float*)d_in[13];
  const float* p2w1 = (const float*)d_in[14], *p2b1 = (const float*)d_in[15];
  const float* p2w2 = (const float*)d_in[16], *p2b2 = (const float*)d_in[17];
  const float* p3w1 = (const float*)d_in[18], *p3b1 = (const float*)d_in[19];
  const float* p3w2 = (const float*)d_in[20], *p3b2 = (const float*)d_in[21];
  const float* ignw = (const float*)d_in[22], *ignb = (const float*)d_in[23];
  const float* cw1 = (const float*)d_in[24], *cb1 = (const float*)d_in[25];
  const float* cw2 = (const float*)d_in[26];
  const float* ndw1 = (const float*)d_in[27], *ndb1 = (const float*)d_in[28];
  const float* ndw2 = (const float*)d_in[29], *ndb2 = (const float*)d_in[30];

  // ---- workspace layout (~162 MB) ----
  char* ws = (char*)d_ws;
  __hip_bfloat16* D1d  = (__hip_bfloat16*)(ws + 0);          // [64][512][512] = 33,554,432 B
  __hip_bfloat16* S    = (__hip_bfloat16*)(ws + 0);          // cell-major S aliases dead D1d
  __hip_bfloat16* D2dT = (__hip_bfloat16*)(ws + 33554432);   // 33,554,432 B
  __hip_bfloat16* S_fij = (__hip_bfloat16*)(ws + 67108864);  // 33,554,432 B
  float* row_part = (float*)(ws + 100663296);                // [32][512][128] = 8,388,608 B
  float* col_part = (float*)(ws + 117440512);                // [32][512][128]
  // ---- single zero-memset block [134,217,728 .. 140,910,608) ----
  float* Tc    = (float*)(ws + 134217728);                   // [16384][96] = 6,291,456 B
  int*   nC    = (int*)(ws + 140509184);                     // 1 int (+pad to 16)
  float* A     = (float*)(ws + 140509200);                   // 32768 floats
  float* B     = (float*)(ws + 140640272);                   // 32768 floats
  float* seg   = (float*)(ws + 140771344);                   // 1536 floats
  float* cnt   = (float*)(ws + 140777488);                   // 512 floats
  float* nb_t0 = (float*)(ws + 140779536);                   // 32768 floats -> end 140,910,608
  // ---- rest ----
  int*   slotmap  = (int*)(ws + 140910608);                  // 262144 ints (0xFF)
  int*   slotmapT = (int*)(ws + 141959184);                  // 262144 ints (0xFF)
  int*   cells    = (int*)(ws + 143007760);                  // 16384 ints
  float* D1       = (float*)(ws + 143073296);                // [16384][64]
  float* D2       = (float*)(ws + 147267600);                // [16384][64]
  float* TWc      = (float*)(ws + 151461904);                // [16384][128]
  float* c1       = (float*)(ws + 159850512);                // 64
  float* c2       = (float*)(ws + 159850768);                // 64
  float* u        = (float*)(ws + 159851024);                // [512][128]
  float* v        = (float*)(ws + 160113168);                // [512][128]
  float* coord_diff  = (float*)(ws + 160375312);             // [512][3]
  float* efn         = (float*)(ws + 160381456);             // [512][64]
  float* diag_silu   = (float*)(ws + 160512528);             // [512][128]
  float* rowsum_silu = (float*)(ws + 160774672);
  float* colsum_silu = (float*)(ws + 161036816);
  float* diag_T      = (float*)(ws + 161298960);             // [512][64]
  float* row_T       = (float*)(ws + 161430032);
  float* col_T       = (float*)(ws + 161561104);
  float* tot         = (float*)(ws + 161692176);             // 64
  float* tr          = (float*)(ws + 161692432);             // 64
  float* nb_t1       = (float*)(ws + 161692688);             // [512][64]
  __hip_bfloat16* Wt = (__hip_bfloat16*)(ws + 161823760);    // [128][64] -> end 161,840,144

  float* out_h  = (float*)d_out;
  float* out_x  = out_h + 512 * 64;
  float* out_ea = out_x + 512 * 3;

  hipMemsetAsync(slotmap, 0xFF, 2097152, stream);            // slotmap + slotmapT = -1
  hipMemsetAsync(ws + 134217728, 0, 6692880, stream);        // Tc..nb_t0

  k_edge<<<512, 128, 0, stream>>>(h, x, edges, ew1, eb1, ew2, eb2, coord_diff, efn);
  k_consts<<<1, 128, 0, stream>>>(p1b1, p1w2, p1b2, p2b1, p2w2, p2b2, c1, c2);
  k_prep<<<32, 256, 0, stream>>>(p3w1, Wt);
  k_mark<<<64, 256, 0, stream>>>(nb_edge, slotmap);
  k_compact<<<1024, 256, 0, stream>>>(slotmap, slotmapT, cells, nC);
  k_scatterT<<<8192, 192, 0, stream>>>(nb_edge, slotmap, coord_diff, efn, Tc);
  k_mlp96b<<<2048, 128, 0, stream>>>(cells, nC, Tc,
                                     p1w1, p1b1, p1w2, p1b2,
                                     p2w1, p2b1, p2w2, p2b2,
                                     c1, c2, p3w1, D1, D2, A, B, TWc);
  k_uv<<<dim3(512, 2), 128, 0, stream>>>(A, B, c1, c2, p3w1, p3b1, u, v);
  k_densify<<<dim3(512, 128), 512, 0, stream>>>(slotmap, slotmapT, D1, D2, D1d, D2dT);
  k_einsum_mfma<<<1024, 256, 0, stream>>>(D1d, D2dT, S_fij);
  k_transpose<<<4096, 256, 0, stream>>>(S_fij, S);
  k_tout_mfma<<<1024, 256, 0, stream>>>(S, u, v, TWc, slotmap, Wt,
                                        row_part, col_part, diag_silu);
  k_sumparts<<<512, 256, 0, stream>>>(row_part, col_part, rowsum_silu, colsum_silu);
  k_tout2<<<dim3(512, 3), 64, 0, stream>>>(diag_silu, rowsum_silu, colsum_silu,
                                           p3w2, p3b2, diag_T, row_T, col_T);
  k_totr<<<1, 128, 0, stream>>>(row_T, diag_T, tot, tr);
  k_nbt1<<<512, 64, 0, stream>>>(diag_T, row_T, col_T, tot, tr, ignw, ignb, nb_t1);
  k_edge_out<<<512, 128, 0, stream>>>(edges, coord_diff, nb_t1, edge_attr,
                                      cw1, cb1, cw2, seg, cnt, nb_t0, out_ea);
  k_node_out<<<512, 128, 0, stream>>>(h, x, seg, cnt, nb_t0,
                                      ndw1, ndb1, ndw2, ndb2, out_h, out_x);
}